// Round 9
// baseline (491.739 us; speedup 1.0000x reference)
//
#include <hip/hip_runtime.h>
#include <hip/hip_bf16.h>
#include <math.h>

// Problem constants
#define B_   32
#define S_   128
#define V_   30000
#define D_   300
#define P_   200
#define NT   8192         // 2*B*S token rows: x1 rows 0..4095, x2 rows 4096..8191
#define NT1  4096

typedef __hip_bfloat16 bf16;
typedef __attribute__((ext_vector_type(8))) __bf16 bf16x8;
typedef __attribute__((ext_vector_type(4))) float f32x4;

__device__ __forceinline__ float b2f(bf16 v) { return __bfloat162float(v); }
__device__ __forceinline__ short f2s(float v) { bf16 h = __float2bfloat16(v); return *(short*)&h; }
__device__ __forceinline__ float s2f(short s) { bf16 h; *(short*)&h = s; return __bfloat162float(h); }

// ---------------------------------------------------------------------------
// Fused weight conversion (8 standard matrices): fp32 [K][N] (optionally two
// sources concat along N) -> bf16 WT[Npad][Kpad], zero-padded (Npad mult 64).
// ---------------------------------------------------------------------------
struct ConvTable {
    const float* W1[8]; const float* W2[8]; bf16* dst[8];
    int K[8], N1[8], N2[8], Kpad[8];
    unsigned long long base[8]; unsigned long long total;
};

__global__ void k_convw(ConvTable T) {
    unsigned long long idx = (unsigned long long)blockIdx.x * 256 + threadIdx.x;
    if (idx >= T.total) return;
    int e = 0;
#pragma unroll
    for (int i = 1; i < 8; ++i) if (idx >= T.base[i]) e = i;
    unsigned long long local = idx - T.base[e];
    int Kpad = T.Kpad[e];
    int n = (int)(local / Kpad);
    int k = (int)(local - (unsigned long long)n * Kpad);
    float v = 0.f;
    if (k < T.K[e]) {
        if (n < T.N1[e]) v = T.W1[e][(size_t)k * T.N1[e] + n];
        else if (n < T.N1[e] + T.N2[e]) v = T.W2[e][(size_t)k * T.N2[e] + (n - T.N1[e])];
    }
    T.dst[e][local] = __float2bfloat16(v);
}

// ---------------------------------------------------------------------------
// Misc conversions in one dispatch:
//  [0, 245760): combined cmp_W1 -> dstc[256][960]
//     Cat@W1 = E@(W1a+W1c) + ATT@(W1b-W1c) + EA@W1d (300-row blocks a,b,c,d)
//  [245760, ...): fp32 transposes for skinny tail (T1 200x800, T2 200x200,
//     T3 3x200)
// ---------------------------------------------------------------------------
__global__ void k_convmisc(const float* __restrict__ Wc, bf16* __restrict__ dstc,
                           const float* __restrict__ A1w, const float* __restrict__ A2w,
                           const float* __restrict__ Ow,
                           float* __restrict__ T1, float* __restrict__ T2,
                           float* __restrict__ T3) {
    int idx = blockIdx.x * 256 + threadIdx.x;
    if (idx < 245760) {
        int n = idx / 960, k = idx - n * 960;
        int sel = k / 320, kc = k - sel * 320;
        float v = 0.f;
        if (kc < 300 && n < 200) {
            if (sel == 0)      v = Wc[(size_t)kc * 200 + n] + Wc[(size_t)(600 + kc) * 200 + n];
            else if (sel == 1) v = Wc[(size_t)(300 + kc) * 200 + n] - Wc[(size_t)(600 + kc) * 200 + n];
            else               v = Wc[(size_t)(900 + kc) * 200 + n];
        }
        dstc[idx] = __float2bfloat16(v);
    } else {
        int l = idx - 245760;
        if (l < 160000)       T1[l] = A1w[(size_t)(l % 800) * 200 + l / 800];
        else if (l < 200000)  { int m = l - 160000; T2[m] = A2w[(size_t)(m % 200) * 200 + m / 200]; }
        else if (l < 200600)  { int m = l - 200000; T3[m] = Ow[(size_t)(m % 200) * 3 + m / 200]; }
    }
}

// ---------------------------------------------------------------------------
// Skinny GEMM for tiny M: one wave per output element (validated round 6).
// ---------------------------------------------------------------------------
__global__ __launch_bounds__(256) void k_skinny(
    const float* __restrict__ A, const float* __restrict__ WT,
    const float* __restrict__ bias, float* __restrict__ C,
    int M, int N, int K, int act) {
    int wave = (blockIdx.x * 256 + threadIdx.x) >> 6;
    int lane = threadIdx.x & 63;
    if (wave >= M * N) return;
    int m = wave / N, n = wave - m * N;
    const float4* a4 = (const float4*)(A + (size_t)m * K);
    const float4* w4 = (const float4*)(WT + (size_t)n * K);
    int K4 = K >> 2;
    float acc = 0.f;
    for (int i = lane; i < K4; i += 64) {
        float4 av = a4[i], wv = w4[i];
        acc += av.x * wv.x + av.y * wv.y + av.z * wv.z + av.w * wv.w;
    }
#pragma unroll
    for (int off = 32; off > 0; off >>= 1) acc += __shfl_down(acc, off, 64);
    if (lane == 0) {
        float v = acc + bias[n];
        if (act == 1) v = fmaxf(v, 0.f);
        C[(size_t)m * N + n] = v;
    }
}

// ---------------------------------------------------------------------------
// Fused MFMA GEMM. Tile 64(M) x 64(N), 4 waves in 2x2, each 32x32 via
// 16x16x32 MFMA. BK=32. WT pre-transposed/padded [Npad][Kpad].
// AMODE: 0 = plain bf16 A (ld lda)
//        1 = embed gather: A-rows gathered from fp32 emb via tok1/tok2,
//            K=300; blockIdx.x==0 persists bf16 rows to WB.
//        2 = fused highway: a = t*h + (1-t)*x with h=A[m][k], t=A[m][nseg+k]
//            (ld lda), x=A2[m][k] (ld nseg); blockIdx.x==0 persists to WB.
//        3 = virtual 3-seg K-concat {A, A2, A3}, each [M,300], 320-pad segs.
//        4 = dual: column-half h=blockIdx.x>>2 selects {A+200h, WT/WT2,
//            C/C2, bias1/bias2}; bn local = (blockIdx.x&3)*64.
// Epilogue: cols [0,N1) bias1/act1, [N1,Ntot) bias2/act2; 1=relu 2=sigmoid.
// ---------------------------------------------------------------------------
#define TKP 40

template <int AMODE>
__global__ __launch_bounds__(256) void k_gemm(
    const bf16* __restrict__ A, const bf16* __restrict__ A2,
    const bf16* __restrict__ A3, int lda, int nseg,
    const int* __restrict__ tok1, const int* __restrict__ tok2,
    const float* __restrict__ emb,
    const bf16* __restrict__ WT, const bf16* __restrict__ WT2, int Kpad, int K,
    bf16* __restrict__ C, bf16* __restrict__ C2, int ldc, int Ntot, int N1,
    const float* __restrict__ bias1, const float* __restrict__ bias2,
    int act1, int act2, bf16* __restrict__ WB)
{
    __shared__ short As[64][TKP];
    __shared__ short Bs[64][TKP];
    int tid = threadIdx.x;
    int w = tid >> 6, lane = tid & 63, quad = lane >> 4, l16 = lane & 15;
    int bm = blockIdx.y * 64;
    int half = 0, bn;
    if (AMODE == 4) { half = blockIdx.x >> 2; bn = (blockIdx.x & 3) * 64; }
    else bn = blockIdx.x * 64;
    const short* Wsh = (const short*)((AMODE == 4 && half) ? WT2 : WT);
    bf16* Cl = (AMODE == 4 && half) ? C2 : C;
    int wr = (w & 1) * 32, wc = (w >> 1) * 32;
    int ar = tid >> 2, ac = (tid & 3) * 8;   // A: row 0..63, k-chunk of 8
    // (B uses the same split: row=ar, k-chunk=ac)

    const short* Abase = (const short*)A + (AMODE == 4 ? half * 200 : 0);
    int gm = bm + ar;
    int tok = 0;
    if (AMODE == 1) {
        tok = (gm < NT1) ? tok1[gm] : tok2[gm - NT1];
        if ((unsigned)tok >= (unsigned)V_) tok = 0;
    }

    f32x4 acc[2][2];
#pragma unroll
    for (int i = 0; i < 2; ++i)
#pragma unroll
        for (int j = 0; j < 2; ++j)
#pragma unroll
            for (int r = 0; r < 4; ++r) acc[i][j][r] = 0.f;

    short pa[8], ph[8], pt[8], px[8], pb[8];

    auto loadA = [&](int k0) {
        if (AMODE == 0 || AMODE == 4) {
            int k = k0 + ac;
            const short* src = Abase + (size_t)gm * lda + k;
            if (k + 8 <= K) {
                *(short4*)&pa[0] = ((const short4*)src)[0];
                *(short4*)&pa[4] = ((const short4*)src)[1];
            } else {
#pragma unroll
                for (int i = 0; i < 8; ++i) pa[i] = (k + i < K) ? src[i] : (short)0;
            }
        } else if (AMODE == 1) {
            int k = k0 + ac;
            const float* src = emb + (size_t)tok * 300 + k;
            float f[8];
            if (k + 8 <= K) {
                *(float4*)&f[0] = ((const float4*)src)[0];
                *(float4*)&f[4] = ((const float4*)src)[1];
            } else {
#pragma unroll
                for (int i = 0; i < 8; ++i) f[i] = (k + i < K) ? src[i] : 0.f;
            }
#pragma unroll
            for (int i = 0; i < 8; ++i) pa[i] = f2s(f[i]);
        } else if (AMODE == 2) {
            int k = k0 + ac;
            const short* hs = (const short*)A + (size_t)gm * lda + k;
            const short* ts = hs + nseg;
            const short* xs = (const short*)A2 + (size_t)gm * nseg + k;
            if (k + 8 <= K) {
                *(short4*)&ph[0] = ((const short4*)hs)[0];
                *(short4*)&ph[4] = ((const short4*)hs)[1];
                *(short4*)&pt[0] = ((const short4*)ts)[0];
                *(short4*)&pt[4] = ((const short4*)ts)[1];
                *(short4*)&px[0] = ((const short4*)xs)[0];
                *(short4*)&px[4] = ((const short4*)xs)[1];
            } else {
#pragma unroll
                for (int i = 0; i < 8; ++i) {
                    bool ok = (k + i < K);
                    ph[i] = ok ? hs[i] : (short)0;
                    pt[i] = ok ? ts[i] : (short)0;
                    px[i] = ok ? xs[i] : (short)0;
                }
            }
        } else {  // 3
            int sel = k0 / 320;                     // wave-uniform
            const short* base = (sel == 0) ? (const short*)A
                              : (sel == 1) ? (const short*)A2 : (const short*)A3;
            int k = (k0 - sel * 320) + ac;
            const short* src = base + (size_t)gm * 300 + k;
            if (k + 8 <= 300) {
                *(short4*)&pa[0] = ((const short4*)src)[0];
                *(short4*)&pa[4] = ((const short4*)src)[1];
            } else {
#pragma unroll
                for (int i = 0; i < 8; ++i) pa[i] = (k + i < 300) ? src[i] : (short)0;
            }
        }
    };
    auto loadB = [&](int k0) {
        const short* src = Wsh + (size_t)(bn + ar) * Kpad + k0 + ac;
        *(short4*)&pb[0] = ((const short4*)src)[0];
        *(short4*)&pb[4] = ((const short4*)src)[1];
    };
    auto commit = [&](int k0) {
        short cv[8];
        if (AMODE == 2) {
#pragma unroll
            for (int i = 0; i < 8; ++i) {
                float h = s2f(ph[i]), t = s2f(pt[i]), x = s2f(px[i]);
                cv[i] = f2s(t * h + (1.f - t) * x);
            }
        } else {
#pragma unroll
            for (int i = 0; i < 8; ++i) cv[i] = pa[i];
        }
        *(short4*)&As[ar][ac] = *(short4*)&cv[0];
        *(short4*)&As[ar][ac + 4] = *(short4*)&cv[4];
        *(short4*)&Bs[ar][ac] = *(short4*)&pb[0];
        *(short4*)&Bs[ar][ac + 4] = *(short4*)&pb[4];
        if ((AMODE == 1 || AMODE == 2) && blockIdx.x == 0) {
            int k = k0 + ac;
            short* dst = (short*)WB + (size_t)gm * K + k;
            if (k + 8 <= K) {
                *(short4*)dst = *(short4*)&cv[0];
                *(short4*)(dst + 4) = *(short4*)&cv[4];
            } else {
#pragma unroll
                for (int i = 0; i < 8; ++i) if (k + i < K) dst[i] = cv[i];
            }
        }
    };

    loadA(0); loadB(0);
    for (int k0 = 0; k0 < Kpad; k0 += 32) {
        commit(k0);
        __syncthreads();
        if (k0 + 32 < Kpad) { loadA(k0 + 32); loadB(k0 + 32); }
        {
            bf16x8 a[2], b[2];
#pragma unroll
            for (int mt = 0; mt < 2; ++mt)
                a[mt] = *(const bf16x8*)&As[wr + mt * 16 + l16][quad * 8];
#pragma unroll
            for (int nt = 0; nt < 2; ++nt)
                b[nt] = *(const bf16x8*)&Bs[wc + nt * 16 + l16][quad * 8];
#pragma unroll
            for (int mt = 0; mt < 2; ++mt)
#pragma unroll
                for (int nt = 0; nt < 2; ++nt)
                    acc[mt][nt] = __builtin_amdgcn_mfma_f32_16x16x32_bf16(a[mt], b[nt], acc[mt][nt], 0, 0, 0);
        }
        __syncthreads();
    }
#pragma unroll
    for (int mt = 0; mt < 2; ++mt) {
        int row = bm + wr + mt * 16 + quad * 4;
#pragma unroll
        for (int nt = 0; nt < 2; ++nt) {
            int col = bn + wc + nt * 16 + l16;
            if (col >= Ntot) continue;
            float bv; int act;
            if (AMODE == 4) { bv = ((half ? bias2 : bias1))[col]; act = act1; }
            else if (col < N1) { bv = bias1[col]; act = act1; }
            else { bv = bias2[col - N1]; act = act2; }
#pragma unroll
            for (int r = 0; r < 4; ++r) {
                float v = acc[mt][nt][r] + bv;
                if (act == 1) v = fmaxf(v, 0.f);
                else if (act == 2) v = 1.f / (1.f + expf(-v));
                Cl[(size_t)(row + r) * ldc + col] = __float2bfloat16(v);
            }
        }
    }
}

// ---------------------------------------------------------------------------
// Transpose x2-halves of two [NT,P] matrices into [B,P,S]; y selects (P,Q).
// ---------------------------------------------------------------------------
__global__ void k_transpose2(const bf16* __restrict__ srcP, bf16* __restrict__ dstP,
                             const bf16* __restrict__ srcQ, bf16* __restrict__ dstQ) {
    int idx = blockIdx.x * 256 + threadIdx.x;
    if (idx >= B_ * P_ * S_) return;
    const bf16* src = blockIdx.y ? srcQ : srcP;
    bf16* dst = blockIdx.y ? dstQ : dstP;
    int j = idx & (S_ - 1);
    int rest = idx >> 7;
    int p = rest % P_;
    int b = rest / P_;
    dst[idx] = src[((size_t)(b * S_ + j)) * P_ + p];
}

// ---------------------------------------------------------------------------
// sim kernel (validated round 7): i-tiled, LDS broadcast, fast rcp.
// ---------------------------------------------------------------------------
__global__ __launch_bounds__(256) void k_sim2(const bf16* __restrict__ Pmat,
                                              const bf16* __restrict__ Qmat,
                                              const bf16* __restrict__ PT,
                                              const bf16* __restrict__ QT,
                                              float* __restrict__ SIM) {
    __shared__ float qp[8][P_][2];
    int blk = blockIdx.x;
    int b = blk >> 4;
    int it = blk & 15;
    int tid = threadIdx.x;
    int j = tid & 127, h = tid >> 7;
    int row0 = b * 128 + it * 8;
    for (int x = tid; x < 8 * P_; x += 256) {
        int r = x / P_, c = x - r * P_;
        qp[r][c][0] = b2f(Qmat[(size_t)(row0 + r) * P_ + c]);
        qp[r][c][1] = b2f(Pmat[(size_t)(row0 + r) * P_ + c]);
    }
    __syncthreads();
    const bf16* ptb = PT + (size_t)b * P_ * S_;
    const bf16* qtb = QT + (size_t)b * P_ * S_;
    float acc[4] = {0.f, 0.f, 0.f, 0.f};
    for (int p = 0; p < P_; ++p) {
        float v = b2f(ptb[p * S_ + j]);
        float u = b2f(qtb[p * S_ + j]);
#pragma unroll
        for (int r = 0; r < 4; ++r) {
            int i = h * 4 + r;
            float2 w = *(const float2*)&qp[i][p][0];
            float d = w.x - u;
            acc[r] += w.y * v + __builtin_amdgcn_rcpf(1.f + fabsf(d));
        }
    }
#pragma unroll
    for (int r = 0; r < 4; ++r) {
        int i = it * 8 + h * 4 + r;
        SIM[((size_t)(b * 128 + i)) * S_ + j] = acc[r];
    }
}

// ---------------------------------------------------------------------------
// Merged softmax-weighted average + fused EA=E*ATT (validated round 8).
// ---------------------------------------------------------------------------
__global__ __launch_bounds__(256) void k_av2(const float* __restrict__ SIM,
                                             const bf16* __restrict__ E,
                                             bf16* __restrict__ OUT,
                                             bf16* __restrict__ EA) {
    int blk = blockIdx.x;
    int kind = blk >> 12;
    int blk2 = blk & 4095;
    int b = blk2 >> 7, r = blk2 & 127;
    int t = threadIdx.x;
    __shared__ float w[S_];
    __shared__ float red[S_];
    float x = 0.f;
    if (t < 128) {
        x = (kind == 0) ? SIM[(size_t)blk2 * S_ + t]
                        : SIM[((size_t)b * S_ + t) * S_ + r];
        red[t] = x;
    }
    __syncthreads();
    for (int s = 64; s > 0; s >>= 1) {
        if (t < s) red[t] = fmaxf(red[t], red[t + s]);
        __syncthreads();
    }
    float mx = red[0];
    __syncthreads();
    float ex = 0.f;
    if (t < 128) { ex = expf(x - mx); red[t] = ex; }
    __syncthreads();
    for (int s = 64; s > 0; s >>= 1) {
        if (t < s) red[t] += red[t + s];
        __syncthreads();
    }
    if (t < 128) w[t] = ex / red[0];
    __syncthreads();
    if (t < 150) {
        int orow_idx = (kind == 0) ? blk2 : (NT1 + blk2);
        const bf16* Esrc = E + (kind == 0 ? (size_t)NT1 * D_ : 0) + (size_t)b * S_ * D_;
        const unsigned short* ebase = (const unsigned short*)Esrc + 2 * t;
        float a0 = 0.f, a1 = 0.f;
        for (int s = 0; s < S_; ++s) {
            unsigned int uv = *(const unsigned int*)(ebase + (size_t)s * D_);
            float lo = __uint_as_float(uv << 16);
            float hi = __uint_as_float(uv & 0xffff0000u);
            float ws = w[s];
            a0 += ws * lo;
            a1 += ws * hi;
        }
        unsigned int o = (unsigned int)(unsigned short)f2s(a0)
                       | ((unsigned int)(unsigned short)f2s(a1) << 16);
        *(unsigned int*)((unsigned short*)OUT + (size_t)orow_idx * D_ + 2 * t) = o;
        unsigned int ev = *(const unsigned int*)((const unsigned short*)E + (size_t)orow_idx * D_ + 2 * t);
        float e0 = __uint_as_float(ev << 16);
        float e1 = __uint_as_float(ev & 0xffff0000u);
        unsigned int o2 = (unsigned int)(unsigned short)f2s(a0 * e0)
                        | ((unsigned int)(unsigned short)f2s(a1 * e1) << 16);
        *(unsigned int*)((unsigned short*)EA + (size_t)orow_idx * D_ + 2 * t) = o2;
    }
}

// ---------------------------------------------------------------------------
// Pool with fused final highway: v = t*h+(1-t)*x from HT [NT,400] (h|t) and
// X [NT,200]; out[b] = concat(max_i v1, max_j v2, sum_i v1, sum_j v2).
// ---------------------------------------------------------------------------
__global__ __launch_bounds__(256) void k_pool2(const bf16* __restrict__ HT,
                                               const bf16* __restrict__ X,
                                               float* __restrict__ OUT) {
    int b = blockIdx.x;
    int c = threadIdx.x;
    if (c >= P_) return;
    float mx1 = -INFINITY, mx2 = -INFINITY, s1 = 0.f, s2 = 0.f;
    for (int i = 0; i < S_; ++i) {
        int r1 = b * S_ + i, r2 = NT1 + b * S_ + i;
        float h1 = b2f(HT[(size_t)r1 * 400 + c]);
        float t1 = b2f(HT[(size_t)r1 * 400 + 200 + c]);
        float x1v = b2f(X[(size_t)r1 * 200 + c]);
        float v1 = t1 * h1 + (1.f - t1) * x1v;
        mx1 = fmaxf(mx1, v1); s1 += v1;
        float h2 = b2f(HT[(size_t)r2 * 400 + c]);
        float t2 = b2f(HT[(size_t)r2 * 400 + 200 + c]);
        float x2v = b2f(X[(size_t)r2 * 200 + c]);
        float v2 = t2 * h2 + (1.f - t2) * x2v;
        mx2 = fmaxf(mx2, v2); s2 += v2;
    }
    float* o = OUT + (size_t)b * 4 * P_;
    o[c] = mx1; o[P_ + c] = mx2; o[2 * P_ + c] = s1; o[3 * P_ + c] = s2;
}

// Sentinel fill (diagnostic: absmax ~555 => ws_size too small)
__global__ void k_fillf(float* dst, int n, float v) {
    int i = blockIdx.x * 256 + threadIdx.x;
    if (i < n) dst[i] = v;
}

// ---------------------------------------------------------------------------
// Launch
// ---------------------------------------------------------------------------
extern "C" void kernel_launch(void* const* d_in, const int* in_sizes, int n_in,
                              void* d_out, int out_size, void* d_ws, size_t ws_size,
                              hipStream_t stream) {
    const int* x1 = (const int*)d_in[0];
    const int* x2 = (const int*)d_in[1];
    const float* emb = (const float*)d_in[2];
    const float *hw1_Wh = (const float*)d_in[3],  *hw1_bh = (const float*)d_in[4];
    const float *hw1_Wt = (const float*)d_in[5],  *hw1_bt = (const float*)d_in[6];
    const float *hw2_Wh = (const float*)d_in[7],  *hw2_bh = (const float*)d_in[8];
    const float *hw2_Wt = (const float*)d_in[9],  *hw2_bt = (const float*)d_in[10];
    const float *mul_W1 = (const float*)d_in[11], *mul_b1 = (const float*)d_in[12];
    const float *mul_W2 = (const float*)d_in[13], *mul_b2 = (const float*)d_in[14];
    const float *dist_W1 = (const float*)d_in[15], *dist_b1 = (const float*)d_in[16];
    const float *dist_W2 = (const float*)d_in[17], *dist_b2 = (const float*)d_in[18];
    const float *cmp_W1 = (const float*)d_in[19], *cmp_b1 = (const float*)d_in[20];
    const float *cmp_W2 = (const float*)d_in[21], *cmp_b2 = (const float*)d_in[22];
    const float *chw1_Wh = (const float*)d_in[23], *chw1_bh = (const float*)d_in[24];
    const float *chw1_Wt = (const float*)d_in[25], *chw1_bt = (const float*)d_in[26];
    const float *chw2_Wh = (const float*)d_in[27], *chw2_bh = (const float*)d_in[28];
    const float *chw2_Wt = (const float*)d_in[29], *chw2_bt = (const float*)d_in[30];
    const float *agg_W1 = (const float*)d_in[31], *agg_b1 = (const float*)d_in[32];
    const float *agg_W2 = (const float*)d_in[33], *agg_b2 = (const float*)d_in[34];
    const float *out_W = (const float*)d_in[35], *out_b = (const float*)d_in[36];

    // ---- Workspace layout (bf16 elems) ----
    const size_t nED = (size_t)NT * D_;        // 2,457,600
    const size_t nEP = (size_t)NT * P_;        // 1,638,400
    const size_t nCht = (size_t)NT * 600;      // 4,915,200
    const size_t nTR = (size_t)B_ * P_ * S_;   //   819,200
    const size_t nWT = 1171456;                // converted bf16 weights (incl c1)
    size_t bf16_elems = 4 * nED + 2 * nEP + 2 * nCht + nWT;   // 24,109,056
    size_t f32_elems = (size_t)B_ * 4 * P_ + 2 * (size_t)B_ * P_ + 200600;
    size_t need = bf16_elems * 2 + f32_elems * 4 + 64;
    if (ws_size < need) {
        k_fillf<<<dim3(1), dim3(256), 0, stream>>>((float*)d_out, B_ * 3, 555.f);
        return;
    }
    bf16* EbA = (bf16*)d_ws;            // embed E; later EA = E*ATT
    bf16* EbB = EbA + nED;              // X1 (after hwy1)
    bf16* EbC = EbB + nED;              // X2 (final E)
    bf16* A2b = EbC + nED;              // ATT
    bf16* Pb  = A2b + nED;              // mul proj -> Vv0 (cmp out)
    bf16* Qb  = Pb + nEP;               // dist proj -> Vv1 (after chw1)
    bf16* ChtA = Qb + nEP;              // [NT,600] h|t / hidden / ch out
    bf16* ChtB = ChtA + nCht;           // [NT,600] h|t / PT,QT,SIM / ch1 out
    bf16* WTp = ChtB + nCht;            // converted bf16 weights
    float* POOL = (float*)(WTp + nWT);
    float* G1 = POOL + (size_t)B_ * 4 * P_;
    float* G2 = G1 + (size_t)B_ * P_;
    float* WT_a1 = G2 + (size_t)B_ * P_;  // [200][800]
    float* WT_a2 = WT_a1 + 160000;        // [200][200]
    float* WT_o  = WT_a2 + 40000;         // [3][200]
    // overlays inside ChtB:
    bf16* PTb = ChtB;
    bf16* QTb = ChtB + nTR;
    float* SIM = (float*)(ChtB + 2 * nTR);

    // converted-weight sub-buffers (elems), Npad mult of 64
    bf16* WT_hw1 = WTp + 0;        // 640x320
    bf16* WT_hw2 = WTp + 204800;   // 640x320
    bf16* WT_md  = WTp + 409600;   // 448x320 (mul_W1 | dist_W1)
    bf16* WT_m2  = WTp + 552960;   // 256x224
    bf16* WT_d2  = WTp + 610304;   // 256x224
    bf16* WT_c2  = WTp + 667648;   // 256x224
    bf16* WT_ch1 = WTp + 724992;   // 448x224 (chw1_Wh | chw1_Wt)
    bf16* WT_ch2 = WTp + 825344;   // 448x224
    bf16* WT_c1  = WTp + 925696;   // 256x960 (combined cmp_W1)

    dim3 blk256(256);

    // 0. weight conversions (2 dispatches)
    ConvTable T;
    const float* s1[8] = {hw1_Wh, hw2_Wh, mul_W1, mul_W2, dist_W2, cmp_W2, chw1_Wh, chw2_Wh};
    const float* s2[8] = {hw1_Wt, hw2_Wt, dist_W1, nullptr, nullptr, nullptr, chw1_Wt, chw2_Wt};
    bf16* dsts[8] = {WT_hw1, WT_hw2, WT_md, WT_m2, WT_d2, WT_c2, WT_ch1, WT_ch2};
    int Ks[8]  = {300, 300, 300, 200, 200, 200, 200, 200};
    int N1s[8] = {300, 300, 200, 200, 200, 200, 200, 200};
    int N2s[8] = {300, 300, 200, 0, 0, 0, 200, 200};
    int Kps[8] = {320, 320, 320, 224, 224, 224, 224, 224};
    int Nps[8] = {640, 640, 448, 256, 256, 256, 448, 448};
    unsigned long long base = 0;
    for (int i = 0; i < 8; ++i) {
        T.W1[i] = s1[i]; T.W2[i] = s2[i]; T.dst[i] = dsts[i];
        T.K[i] = Ks[i]; T.N1[i] = N1s[i]; T.N2[i] = N2s[i]; T.Kpad[i] = Kps[i];
        T.base[i] = base;
        base += (unsigned long long)Kps[i] * Nps[i];
    }
    T.total = base;   // 925,696
    k_convw<<<dim3((unsigned)((base + 255) / 256)), blk256, 0, stream>>>(T);
    k_convmisc<<<dim3((245760 + 200600 + 255) / 256), blk256, 0, stream>>>(
        cmp_W1, WT_c1, agg_W1, agg_W2, out_W, WT_a1, WT_a2, WT_o);

    // 1. hw1 GEMM (embed fused): emb-gather -> ChtA h1|t1; persists E -> EbA
    k_gemm<1><<<dim3(10, 128), blk256, 0, stream>>>(
        nullptr, nullptr, nullptr, 0, 0, x1, x2, emb,
        WT_hw1, nullptr, 320, 300, ChtA, nullptr, 600, 600, 300,
        hw1_bh, hw1_bt, 1, 2, EbA);

    // 2. hw2 GEMM (hwy1 fused): A = combine(ChtA, EbA) -> ChtB; persists X1 -> EbB
    k_gemm<2><<<dim3(10, 128), blk256, 0, stream>>>(
        ChtA, EbA, nullptr, 600, 300, nullptr, nullptr, nullptr,
        WT_hw2, nullptr, 320, 300, ChtB, nullptr, 600, 600, 300,
        hw2_bh, hw2_bt, 1, 2, EbB);

    // 3. mul+dist W1 GEMM (hwy2 fused): A = combine(ChtB, EbB) -> ChtA [NT,400];
    //    persists X2 -> EbC
    k_gemm<2><<<dim3(7, 128), blk256, 0, stream>>>(
        ChtB, EbB, nullptr, 600, 300, nullptr, nullptr, nullptr,
        WT_md, nullptr, 320, 300, ChtA, nullptr, 400, 400, 200,
        mul_b1, dist_b1, 1, 1, EbC);

    // 4. m2 + d2 dual GEMM: ChtA halves -> Pb, Qb
    k_gemm<4><<<dim3(8, 128), blk256, 0, stream>>>(
        ChtA, nullptr, nullptr, 400, 0, nullptr, nullptr, nullptr,
        WT_m2, WT_d2, 224, 200, Pb, Qb, 200, 200, 200,
        mul_b2, dist_b2, 1, 1, nullptr);

    // 5. transpose x2-halves into ChtB overlay
    int nTRb = (int)((nTR + 255) / 256);
    k_transpose2<<<dim3(nTRb, 2), blk256, 0, stream>>>(
        Pb + (size_t)NT1 * P_, PTb, Qb + (size_t)NT1 * P_, QTb);

    // 6. sim
    k_sim2<<<dim3(B_ * 16), blk256, 0, stream>>>(Pb, Qb, PTb, QTb, SIM);

    // 7. attention (merged beta+alpha) + fused EA; E = EbC
    k_av2<<<dim3(2 * NT1), blk256, 0, stream>>>(SIM, EbC, A2b, EbA);

    // 8. cmp1 GEMM: virtual K-concat {EbC, A2b, EbA(EA)} -> ChtA hidden [NT,200]
    k_gemm<3><<<dim3(4, 128), blk256, 0, stream>>>(
        EbC, A2b, EbA, 300, 0, nullptr, nullptr, nullptr,
        WT_c1, nullptr, 960, 300, ChtA, nullptr, 200, 200, 200,
        cmp_b1, cmp_b1, 1, 1, nullptr);

    // 9. cmp2 GEMM: ChtA -> Pb (Vv0)
    k_gemm<0><<<dim3(4, 128), blk256, 0, stream>>>(
        ChtA, nullptr, nullptr, 200, 0, nullptr, nullptr, nullptr,
        WT_c2, nullptr, 224, 200, Pb, nullptr, 200, 200, 200,
        cmp_b2, cmp_b2, 1, 1, nullptr);

    // 10. ch1 GEMM: Pb -> ChtB h|t [NT,400]
    k_gemm<0><<<dim3(7, 128), blk256, 0, stream>>>(
        Pb, nullptr, nullptr, 200, 0, nullptr, nullptr, nullptr,
        WT_ch1, nullptr, 224, 200, ChtB, nullptr, 400, 400, 200,
        chw1_bh, chw1_bt, 1, 2, nullptr);

    // 11. ch2 GEMM (chw1 fused): A = combine(ChtB, Pb) -> ChtA h|t; persists V1 -> Qb
    k_gemm<2><<<dim3(7, 128), blk256, 0, stream>>>(
        ChtB, Pb, nullptr, 400, 200, nullptr, nullptr, nullptr,
        WT_ch2, nullptr, 224, 200, ChtA, nullptr, 400, 400, 200,
        chw2_bh, chw2_bt, 1, 2, Qb);

    // 12. pool (chw2 fused): combine(ChtA, Qb) pooled -> POOL
    k_pool2<<<dim3(B_), blk256, 0, stream>>>(ChtA, Qb, POOL);

    // 13-15. aggregate ff + final linear: wave-per-output skinny GEMMs
    k_skinny<<<dim3(1600), blk256, 0, stream>>>(POOL, WT_a1, agg_b1, G1, B_, P_, 800, 1);
    k_skinny<<<dim3(1600), blk256, 0, stream>>>(G1, WT_a2, agg_b2, G2, B_, P_, 200, 1);
    k_skinny<<<dim3(24), blk256, 0, stream>>>(G2, WT_o, out_b, (float*)d_out, B_, 3, 200, 0);
}

// Round 10
// 424.838 us; speedup vs baseline: 1.1575x; 1.1575x over previous
//
#include <hip/hip_runtime.h>
#include <hip/hip_bf16.h>
#include <math.h>

// Problem constants
#define B_   32
#define S_   128
#define V_   30000
#define D_   300
#define P_   200
#define NT   8192         // 2*B*S token rows: x1 rows 0..4095, x2 rows 4096..8191
#define NT1  4096

typedef __hip_bfloat16 bf16;
typedef __attribute__((ext_vector_type(8))) __bf16 bf16x8;
typedef __attribute__((ext_vector_type(4))) float f32x4;

__device__ __forceinline__ float b2f(bf16 v) { return __bfloat162float(v); }
__device__ __forceinline__ short f2s(float v) { bf16 h = __float2bfloat16(v); return *(short*)&h; }
__device__ __forceinline__ float s2f(short s) { bf16 h; *(short*)&h = s; return __bfloat162float(h); }

// ---------------------------------------------------------------------------
// Fused weight conversion (8 standard matrices): fp32 [K][N] (optionally two
// sources concat along N) -> bf16 WT[Npad][Kpad], zero-padded (Npad mult 64).
// ---------------------------------------------------------------------------
struct ConvTable {
    const float* W1[8]; const float* W2[8]; bf16* dst[8];
    int K[8], N1[8], N2[8], Kpad[8];
    unsigned long long base[8]; unsigned long long total;
};

__global__ void k_convw(ConvTable T) {
    unsigned long long idx = (unsigned long long)blockIdx.x * 256 + threadIdx.x;
    if (idx >= T.total) return;
    int e = 0;
#pragma unroll
    for (int i = 1; i < 8; ++i) if (idx >= T.base[i]) e = i;
    unsigned long long local = idx - T.base[e];
    int Kpad = T.Kpad[e];
    int n = (int)(local / Kpad);
    int k = (int)(local - (unsigned long long)n * Kpad);
    float v = 0.f;
    if (k < T.K[e]) {
        if (n < T.N1[e]) v = T.W1[e][(size_t)k * T.N1[e] + n];
        else if (n < T.N1[e] + T.N2[e]) v = T.W2[e][(size_t)k * T.N2[e] + (n - T.N1[e])];
    }
    T.dst[e][local] = __float2bfloat16(v);
}

// ---------------------------------------------------------------------------
// Misc conversions in one dispatch: combined cmp_W1 (decomposed) + fp32
// transposes for the skinny tail.
// ---------------------------------------------------------------------------
__global__ void k_convmisc(const float* __restrict__ Wc, bf16* __restrict__ dstc,
                           const float* __restrict__ A1w, const float* __restrict__ A2w,
                           const float* __restrict__ Ow,
                           float* __restrict__ T1, float* __restrict__ T2,
                           float* __restrict__ T3) {
    int idx = blockIdx.x * 256 + threadIdx.x;
    if (idx < 245760) {
        int n = idx / 960, k = idx - n * 960;
        int sel = k / 320, kc = k - sel * 320;
        float v = 0.f;
        if (kc < 300 && n < 200) {
            if (sel == 0)      v = Wc[(size_t)kc * 200 + n] + Wc[(size_t)(600 + kc) * 200 + n];
            else if (sel == 1) v = Wc[(size_t)(300 + kc) * 200 + n] - Wc[(size_t)(600 + kc) * 200 + n];
            else               v = Wc[(size_t)(900 + kc) * 200 + n];
        }
        dstc[idx] = __float2bfloat16(v);
    } else {
        int l = idx - 245760;
        if (l < 160000)       T1[l] = A1w[(size_t)(l % 800) * 200 + l / 800];
        else if (l < 200000)  { int m = l - 160000; T2[m] = A2w[(size_t)(m % 200) * 200 + m / 200]; }
        else if (l < 200600)  { int m = l - 200000; T3[m] = Ow[(size_t)(m % 200) * 3 + m / 200]; }
    }
}

// ---------------------------------------------------------------------------
// Skinny GEMM for tiny M: one wave per output element (validated round 6).
// ---------------------------------------------------------------------------
__global__ __launch_bounds__(256) void k_skinny(
    const float* __restrict__ A, const float* __restrict__ WT,
    const float* __restrict__ bias, float* __restrict__ C,
    int M, int N, int K, int act) {
    int wave = (blockIdx.x * 256 + threadIdx.x) >> 6;
    int lane = threadIdx.x & 63;
    if (wave >= M * N) return;
    int m = wave / N, n = wave - m * N;
    const float4* a4 = (const float4*)(A + (size_t)m * K);
    const float4* w4 = (const float4*)(WT + (size_t)n * K);
    int K4 = K >> 2;
    float acc = 0.f;
    for (int i = lane; i < K4; i += 64) {
        float4 av = a4[i], wv = w4[i];
        acc += av.x * wv.x + av.y * wv.y + av.z * wv.z + av.w * wv.w;
    }
#pragma unroll
    for (int off = 32; off > 0; off >>= 1) acc += __shfl_down(acc, off, 64);
    if (lane == 0) {
        float v = acc + bias[n];
        if (act == 1) v = fmaxf(v, 0.f);
        C[(size_t)m * N + n] = v;
    }
}

// ---------------------------------------------------------------------------
// Fused MFMA GEMM. Tile 64(M) x 64(N), 4 waves in 2x2, each 32x32 via
// 16x16x32 MFMA. BK=32. WT pre-transposed/padded [Npad][Kpad].
// GRID: blockIdx.x = row-tile (XCD-friendly: same-row stripes land on the
// same XCD since gridDim.x=128 ≡ 0 mod 8), blockIdx.y = column stripe.
// AMODE: 0 plain; 1 embed-gather from fp32 emb (persist E to WB at y==0);
//        2 fused highway a=t*h+(1-t)*x (persist to WB at y==0);
//        3 virtual 3-seg K-concat {A,A2,A3} ([M,300], 320-pad segs);
//        4 dual: half=blockIdx.y>>2 selects {A+200h, WT/WT2, C/C2, bias}.
// Epilogue staged through LDS for full-line 128B row writes.
// ---------------------------------------------------------------------------
#define TKP 40

template <int AMODE>
__global__ __launch_bounds__(256) void k_gemm(
    const bf16* __restrict__ A, const bf16* __restrict__ A2,
    const bf16* __restrict__ A3, int lda, int nseg,
    const int* __restrict__ tok1, const int* __restrict__ tok2,
    const float* __restrict__ emb,
    const bf16* __restrict__ WT, const bf16* __restrict__ WT2, int Kpad, int K,
    bf16* __restrict__ C, bf16* __restrict__ C2, int ldc, int Ntot, int N1,
    const float* __restrict__ bias1, const float* __restrict__ bias2,
    int act1, int act2, bf16* __restrict__ WB)
{
    __shared__ short As[64][TKP];
    __shared__ short Bs[64][TKP];
    __shared__ short Cs[64][66];
    int tid = threadIdx.x;
    int w = tid >> 6, lane = tid & 63, quad = lane >> 4, l16 = lane & 15;
    int bm = blockIdx.x * 64;                  // rows on x (XCD locality)
    int half = 0, bn;
    if (AMODE == 4) { half = blockIdx.y >> 2; bn = (blockIdx.y & 3) * 64; }
    else bn = blockIdx.y * 64;
    const short* Wsh = (const short*)((AMODE == 4 && half) ? WT2 : WT);
    bf16* Cl = (AMODE == 4 && half) ? C2 : C;
    int wr = (w & 1) * 32, wc = (w >> 1) * 32;
    int ar = tid >> 2, ac = (tid & 3) * 8;     // stage: row 0..63, k-chunk of 8

    const short* Abase = (const short*)A + (AMODE == 4 ? half * 200 : 0);
    int gm = bm + ar;
    int tok = 0;
    if (AMODE == 1) {
        tok = (gm < NT1) ? tok1[gm] : tok2[gm - NT1];
        if ((unsigned)tok >= (unsigned)V_) tok = 0;
    }

    f32x4 acc[2][2];
#pragma unroll
    for (int i = 0; i < 2; ++i)
#pragma unroll
        for (int j = 0; j < 2; ++j)
#pragma unroll
            for (int r = 0; r < 4; ++r) acc[i][j][r] = 0.f;

    short pa[8], ph[8], pt[8], px[8], pb[8];

    auto loadA = [&](int k0) {
        if (AMODE == 0 || AMODE == 4) {
            int k = k0 + ac;
            const short* src = Abase + (size_t)gm * lda + k;
            if (k + 8 <= K) {
                *(short4*)&pa[0] = ((const short4*)src)[0];
                *(short4*)&pa[4] = ((const short4*)src)[1];
            } else {
#pragma unroll
                for (int i = 0; i < 8; ++i) pa[i] = (k + i < K) ? src[i] : (short)0;
            }
        } else if (AMODE == 1) {
            int k = k0 + ac;
            const float* src = emb + (size_t)tok * 300 + k;
            float f[8];
            if (k + 8 <= K) {
                *(float4*)&f[0] = ((const float4*)src)[0];
                *(float4*)&f[4] = ((const float4*)src)[1];
            } else {
#pragma unroll
                for (int i = 0; i < 8; ++i) f[i] = (k + i < K) ? src[i] : 0.f;
            }
#pragma unroll
            for (int i = 0; i < 8; ++i) pa[i] = f2s(f[i]);
        } else if (AMODE == 2) {
            int k = k0 + ac;
            const short* hs = (const short*)A + (size_t)gm * lda + k;
            const short* ts = hs + nseg;
            const short* xs = (const short*)A2 + (size_t)gm * nseg + k;
            if (k + 8 <= K) {
                *(short4*)&ph[0] = ((const short4*)hs)[0];
                *(short4*)&ph[4] = ((const short4*)hs)[1];
                *(short4*)&pt[0] = ((const short4*)ts)[0];
                *(short4*)&pt[4] = ((const short4*)ts)[1];
                *(short4*)&px[0] = ((const short4*)xs)[0];
                *(short4*)&px[4] = ((const short4*)xs)[1];
            } else {
#pragma unroll
                for (int i = 0; i < 8; ++i) {
                    bool ok = (k + i < K);
                    ph[i] = ok ? hs[i] : (short)0;
                    pt[i] = ok ? ts[i] : (short)0;
                    px[i] = ok ? xs[i] : (short)0;
                }
            }
        } else {  // 3
            int sel = k0 / 320;                 // wave-uniform
            const short* base = (sel == 0) ? (const short*)A
                              : (sel == 1) ? (const short*)A2 : (const short*)A3;
            int k = (k0 - sel * 320) + ac;
            const short* src = base + (size_t)gm * 300 + k;
            if (k + 8 <= 300) {
                *(short4*)&pa[0] = ((const short4*)src)[0];
                *(short4*)&pa[4] = ((const short4*)src)[1];
            } else {
#pragma unroll
                for (int i = 0; i < 8; ++i) pa[i] = (k + i < 300) ? src[i] : (short)0;
            }
        }
    };
    auto loadB = [&](int k0) {
        const short* src = Wsh + (size_t)(bn + ar) * Kpad + k0 + ac;
        *(short4*)&pb[0] = ((const short4*)src)[0];
        *(short4*)&pb[4] = ((const short4*)src)[1];
    };
    auto commit = [&](int k0) {
        short cv[8];
        if (AMODE == 2) {
#pragma unroll
            for (int i = 0; i < 8; ++i) {
                float h = s2f(ph[i]), t = s2f(pt[i]), x = s2f(px[i]);
                cv[i] = f2s(t * h + (1.f - t) * x);
            }
        } else {
#pragma unroll
            for (int i = 0; i < 8; ++i) cv[i] = pa[i];
        }
        *(short4*)&As[ar][ac] = *(short4*)&cv[0];
        *(short4*)&As[ar][ac + 4] = *(short4*)&cv[4];
        *(short4*)&Bs[ar][ac] = *(short4*)&pb[0];
        *(short4*)&Bs[ar][ac + 4] = *(short4*)&pb[4];
        if ((AMODE == 1 || AMODE == 2) && blockIdx.y == 0) {
            int k = k0 + ac;
            short* dst = (short*)WB + (size_t)gm * K + k;
            if (k + 8 <= K) {
                *(short4*)dst = *(short4*)&cv[0];
                *(short4*)(dst + 4) = *(short4*)&cv[4];
            } else {
#pragma unroll
                for (int i = 0; i < 8; ++i) if (k + i < K) dst[i] = cv[i];
            }
        }
    };

    loadA(0); loadB(0);
    for (int k0 = 0; k0 < Kpad; k0 += 32) {
        commit(k0);
        __syncthreads();
        if (k0 + 32 < Kpad) { loadA(k0 + 32); loadB(k0 + 32); }
        {
            bf16x8 a[2], b[2];
#pragma unroll
            for (int mt = 0; mt < 2; ++mt)
                a[mt] = *(const bf16x8*)&As[wr + mt * 16 + l16][quad * 8];
#pragma unroll
            for (int nt = 0; nt < 2; ++nt)
                b[nt] = *(const bf16x8*)&Bs[wc + nt * 16 + l16][quad * 8];
#pragma unroll
            for (int mt = 0; mt < 2; ++mt)
#pragma unroll
                for (int nt = 0; nt < 2; ++nt)
                    acc[mt][nt] = __builtin_amdgcn_mfma_f32_16x16x32_bf16(a[mt], b[nt], acc[mt][nt], 0, 0, 0);
        }
        __syncthreads();
    }
    // ---- epilogue: bias+act into LDS, then full-line coalesced stores
#pragma unroll
    for (int mt = 0; mt < 2; ++mt) {
#pragma unroll
        for (int nt = 0; nt < 2; ++nt) {
            int cl = wc + nt * 16 + l16;
            int col = bn + cl;
            int cc = (col < Ntot) ? col : (Ntot - 1);
            float bv; int act;
            if (AMODE == 4) { bv = (half ? bias2 : bias1)[cc]; act = act1; }
            else if (cc < N1) { bv = bias1[cc]; act = act1; }
            else { bv = bias2[cc - N1]; act = act2; }
#pragma unroll
            for (int r = 0; r < 4; ++r) {
                float v = acc[mt][nt][r] + bv;
                if (act == 1) v = fmaxf(v, 0.f);
                else if (act == 2) v = 1.f / (1.f + expf(-v));
                Cs[wr + mt * 16 + quad * 4 + r][cl] = f2s(v);
            }
        }
    }
    __syncthreads();
    int Nrem = Ntot - bn;                       // valid cols this stripe
#pragma unroll
    for (int it = 0; it < 2; ++it) {
        int chunk = tid + it * 256;             // 0..511
        int rl = chunk >> 3;
        int c8 = (chunk & 7) * 8;
        short* dst = (short*)Cl + (size_t)(bm + rl) * ldc + bn + c8;
        if (c8 + 8 <= Nrem) {
            *(short4*)dst = *(short4*)&Cs[rl][c8];
            *(short4*)(dst + 4) = *(short4*)&Cs[rl][c8 + 4];
        } else {
            for (int i = 0; i < 8; ++i) if (c8 + i < Nrem) dst[i] = Cs[rl][c8 + i];
        }
    }
}

// ---------------------------------------------------------------------------
// Transpose x2-halves of two [NT,P] matrices into [B,P,S]; y selects (P,Q).
// ---------------------------------------------------------------------------
__global__ void k_transpose2(const bf16* __restrict__ srcP, bf16* __restrict__ dstP,
                             const bf16* __restrict__ srcQ, bf16* __restrict__ dstQ) {
    int idx = blockIdx.x * 256 + threadIdx.x;
    if (idx >= B_ * P_ * S_) return;
    const bf16* src = blockIdx.y ? srcQ : srcP;
    bf16* dst = blockIdx.y ? dstQ : dstP;
    int j = idx & (S_ - 1);
    int rest = idx >> 7;
    int p = rest % P_;
    int b = rest / P_;
    dst[idx] = src[((size_t)(b * S_ + j)) * P_ + p];
}

// ---------------------------------------------------------------------------
// sim kernel (validated round 7): i-tiled, LDS broadcast, fast rcp.
// ---------------------------------------------------------------------------
__global__ __launch_bounds__(256) void k_sim2(const bf16* __restrict__ Pmat,
                                              const bf16* __restrict__ Qmat,
                                              const bf16* __restrict__ PT,
                                              const bf16* __restrict__ QT,
                                              float* __restrict__ SIM) {
    __shared__ float qp[8][P_][2];
    int blk = blockIdx.x;
    int b = blk >> 4;
    int it = blk & 15;
    int tid = threadIdx.x;
    int j = tid & 127, h = tid >> 7;
    int row0 = b * 128 + it * 8;
    for (int x = tid; x < 8 * P_; x += 256) {
        int r = x / P_, c = x - r * P_;
        qp[r][c][0] = b2f(Qmat[(size_t)(row0 + r) * P_ + c]);
        qp[r][c][1] = b2f(Pmat[(size_t)(row0 + r) * P_ + c]);
    }
    __syncthreads();
    const bf16* ptb = PT + (size_t)b * P_ * S_;
    const bf16* qtb = QT + (size_t)b * P_ * S_;
    float acc[4] = {0.f, 0.f, 0.f, 0.f};
    for (int p = 0; p < P_; ++p) {
        float v = b2f(ptb[p * S_ + j]);
        float u = b2f(qtb[p * S_ + j]);
#pragma unroll
        for (int r = 0; r < 4; ++r) {
            int i = h * 4 + r;
            float2 w = *(const float2*)&qp[i][p][0];
            float d = w.x - u;
            acc[r] += w.y * v + __builtin_amdgcn_rcpf(1.f + fabsf(d));
        }
    }
#pragma unroll
    for (int r = 0; r < 4; ++r) {
        int i = it * 8 + h * 4 + r;
        SIM[((size_t)(b * 128 + i)) * S_ + j] = acc[r];
    }
}

// ---------------------------------------------------------------------------
// Merged softmax-weighted average + fused EA=E*ATT (validated round 8).
// ---------------------------------------------------------------------------
__global__ __launch_bounds__(256) void k_av2(const float* __restrict__ SIM,
                                             const bf16* __restrict__ E,
                                             bf16* __restrict__ OUT,
                                             bf16* __restrict__ EA) {
    int blk = blockIdx.x;
    int kind = blk >> 12;
    int blk2 = blk & 4095;
    int b = blk2 >> 7, r = blk2 & 127;
    int t = threadIdx.x;
    __shared__ float w[S_];
    __shared__ float red[S_];
    float x = 0.f;
    if (t < 128) {
        x = (kind == 0) ? SIM[(size_t)blk2 * S_ + t]
                        : SIM[((size_t)b * S_ + t) * S_ + r];
        red[t] = x;
    }
    __syncthreads();
    for (int s = 64; s > 0; s >>= 1) {
        if (t < s) red[t] = fmaxf(red[t], red[t + s]);
        __syncthreads();
    }
    float mx = red[0];
    __syncthreads();
    float ex = 0.f;
    if (t < 128) { ex = expf(x - mx); red[t] = ex; }
    __syncthreads();
    for (int s = 64; s > 0; s >>= 1) {
        if (t < s) red[t] += red[t + s];
        __syncthreads();
    }
    if (t < 128) w[t] = ex / red[0];
    __syncthreads();
    if (t < 150) {
        int orow_idx = (kind == 0) ? blk2 : (NT1 + blk2);
        const bf16* Esrc = E + (kind == 0 ? (size_t)NT1 * D_ : 0) + (size_t)b * S_ * D_;
        const unsigned short* ebase = (const unsigned short*)Esrc + 2 * t;
        float a0 = 0.f, a1 = 0.f;
        for (int s = 0; s < S_; ++s) {
            unsigned int uv = *(const unsigned int*)(ebase + (size_t)s * D_);
            float lo = __uint_as_float(uv << 16);
            float hi = __uint_as_float(uv & 0xffff0000u);
            float ws = w[s];
            a0 += ws * lo;
            a1 += ws * hi;
        }
        unsigned int o = (unsigned int)(unsigned short)f2s(a0)
                       | ((unsigned int)(unsigned short)f2s(a1) << 16);
        *(unsigned int*)((unsigned short*)OUT + (size_t)orow_idx * D_ + 2 * t) = o;
        unsigned int ev = *(const unsigned int*)((const unsigned short*)E + (size_t)orow_idx * D_ + 2 * t);
        float e0 = __uint_as_float(ev << 16);
        float e1 = __uint_as_float(ev & 0xffff0000u);
        unsigned int o2 = (unsigned int)(unsigned short)f2s(a0 * e0)
                        | ((unsigned int)(unsigned short)f2s(a1 * e1) << 16);
        *(unsigned int*)((unsigned short*)EA + (size_t)orow_idx * D_ + 2 * t) = o2;
    }
}

// ---------------------------------------------------------------------------
// Pool with fused final highway (validated round 9).
// ---------------------------------------------------------------------------
__global__ __launch_bounds__(256) void k_pool2(const bf16* __restrict__ HT,
                                               const bf16* __restrict__ X,
                                               float* __restrict__ OUT) {
    int b = blockIdx.x;
    int c = threadIdx.x;
    if (c >= P_) return;
    float mx1 = -INFINITY, mx2 = -INFINITY, s1 = 0.f, s2 = 0.f;
    for (int i = 0; i < S_; ++i) {
        int r1 = b * S_ + i, r2 = NT1 + b * S_ + i;
        float h1 = b2f(HT[(size_t)r1 * 400 + c]);
        float t1 = b2f(HT[(size_t)r1 * 400 + 200 + c]);
        float x1v = b2f(X[(size_t)r1 * 200 + c]);
        float v1 = t1 * h1 + (1.f - t1) * x1v;
        mx1 = fmaxf(mx1, v1); s1 += v1;
        float h2 = b2f(HT[(size_t)r2 * 400 + c]);
        float t2 = b2f(HT[(size_t)r2 * 400 + 200 + c]);
        float x2v = b2f(X[(size_t)r2 * 200 + c]);
        float v2 = t2 * h2 + (1.f - t2) * x2v;
        mx2 = fmaxf(mx2, v2); s2 += v2;
    }
    float* o = OUT + (size_t)b * 4 * P_;
    o[c] = mx1; o[P_ + c] = mx2; o[2 * P_ + c] = s1; o[3 * P_ + c] = s2;
}

// Sentinel fill (diagnostic: absmax ~555 => ws_size too small)
__global__ void k_fillf(float* dst, int n, float v) {
    int i = blockIdx.x * 256 + threadIdx.x;
    if (i < n) dst[i] = v;
}

// ---------------------------------------------------------------------------
// Launch
// ---------------------------------------------------------------------------
extern "C" void kernel_launch(void* const* d_in, const int* in_sizes, int n_in,
                              void* d_out, int out_size, void* d_ws, size_t ws_size,
                              hipStream_t stream) {
    const int* x1 = (const int*)d_in[0];
    const int* x2 = (const int*)d_in[1];
    const float* emb = (const float*)d_in[2];
    const float *hw1_Wh = (const float*)d_in[3],  *hw1_bh = (const float*)d_in[4];
    const float *hw1_Wt = (const float*)d_in[5],  *hw1_bt = (const float*)d_in[6];
    const float *hw2_Wh = (const float*)d_in[7],  *hw2_bh = (const float*)d_in[8];
    const float *hw2_Wt = (const float*)d_in[9],  *hw2_bt = (const float*)d_in[10];
    const float *mul_W1 = (const float*)d_in[11], *mul_b1 = (const float*)d_in[12];
    const float *mul_W2 = (const float*)d_in[13], *mul_b2 = (const float*)d_in[14];
    const float *dist_W1 = (const float*)d_in[15], *dist_b1 = (const float*)d_in[16];
    const float *dist_W2 = (const float*)d_in[17], *dist_b2 = (const float*)d_in[18];
    const float *cmp_W1 = (const float*)d_in[19], *cmp_b1 = (const float*)d_in[20];
    const float *cmp_W2 = (const float*)d_in[21], *cmp_b2 = (const float*)d_in[22];
    const float *chw1_Wh = (const float*)d_in[23], *chw1_bh = (const float*)d_in[24];
    const float *chw1_Wt = (const float*)d_in[25], *chw1_bt = (const float*)d_in[26];
    const float *chw2_Wh = (const float*)d_in[27], *chw2_bh = (const float*)d_in[28];
    const float *chw2_Wt = (const float*)d_in[29], *chw2_bt = (const float*)d_in[30];
    const float *agg_W1 = (const float*)d_in[31], *agg_b1 = (const float*)d_in[32];
    const float *agg_W2 = (const float*)d_in[33], *agg_b2 = (const float*)d_in[34];
    const float *out_W = (const float*)d_in[35], *out_b = (const float*)d_in[36];

    // ---- Workspace layout (bf16 elems) ----
    const size_t nED = (size_t)NT * D_;        // 2,457,600
    const size_t nEP = (size_t)NT * P_;        // 1,638,400
    const size_t nCht = (size_t)NT * 600;      // 4,915,200
    const size_t nTR = (size_t)B_ * P_ * S_;   //   819,200
    const size_t nWT = 1171456;                // converted bf16 weights (incl c1)
    size_t bf16_elems = 4 * nED + 2 * nEP + 2 * nCht + nWT;
    size_t f32_elems = (size_t)B_ * 4 * P_ + 2 * (size_t)B_ * P_ + 200600;
    size_t need = bf16_elems * 2 + f32_elems * 4 + 64;
    if (ws_size < need) {
        k_fillf<<<dim3(1), dim3(256), 0, stream>>>((float*)d_out, B_ * 3, 555.f);
        return;
    }
    bf16* EbA = (bf16*)d_ws;            // embed E; later EA = E*ATT
    bf16* EbB = EbA + nED;              // X1 (after hwy1)
    bf16* EbC = EbB + nED;              // X2 (final E)
    bf16* A2b = EbC + nED;              // ATT
    bf16* Pb  = A2b + nED;              // mul proj -> Vv0 (cmp out)
    bf16* Qb  = Pb + nEP;               // dist proj -> Vv1 (after chw1)
    bf16* ChtA = Qb + nEP;              // [NT,600]
    bf16* ChtB = ChtA + nCht;           // [NT,600]
    bf16* WTp = ChtB + nCht;            // converted bf16 weights
    float* POOL = (float*)(WTp + nWT);
    float* G1 = POOL + (size_t)B_ * 4 * P_;
    float* G2 = G1 + (size_t)B_ * P_;
    float* WT_a1 = G2 + (size_t)B_ * P_;  // [200][800]
    float* WT_a2 = WT_a1 + 160000;        // [200][200]
    float* WT_o  = WT_a2 + 40000;         // [3][200]
    // overlays inside ChtB:
    bf16* PTb = ChtB;
    bf16* QTb = ChtB + nTR;
    float* SIM = (float*)(ChtB + 2 * nTR);

    // converted-weight sub-buffers (elems), Npad mult of 64
    bf16* WT_hw1 = WTp + 0;        // 640x320
    bf16* WT_hw2 = WTp + 204800;   // 640x320
    bf16* WT_md  = WTp + 409600;   // 448x320 (mul_W1 | dist_W1)
    bf16* WT_m2  = WTp + 552960;   // 256x224
    bf16* WT_d2  = WTp + 610304;   // 256x224
    bf16* WT_c2  = WTp + 667648;   // 256x224
    bf16* WT_ch1 = WTp + 724992;   // 448x224 (chw1_Wh | chw1_Wt)
    bf16* WT_ch2 = WTp + 825344;   // 448x224
    bf16* WT_c1  = WTp + 925696;   // 256x960 (combined cmp_W1)

    dim3 blk256(256);

    // 0. weight conversions (2 dispatches)
    ConvTable T;
    const float* s1[8] = {hw1_Wh, hw2_Wh, mul_W1, mul_W2, dist_W2, cmp_W2, chw1_Wh, chw2_Wh};
    const float* s2[8] = {hw1_Wt, hw2_Wt, dist_W1, nullptr, nullptr, nullptr, chw1_Wt, chw2_Wt};
    bf16* dsts[8] = {WT_hw1, WT_hw2, WT_md, WT_m2, WT_d2, WT_c2, WT_ch1, WT_ch2};
    int Ks[8]  = {300, 300, 300, 200, 200, 200, 200, 200};
    int N1s[8] = {300, 300, 200, 200, 200, 200, 200, 200};
    int N2s[8] = {300, 300, 200, 0, 0, 0, 200, 200};
    int Kps[8] = {320, 320, 320, 224, 224, 224, 224, 224};
    int Nps[8] = {640, 640, 448, 256, 256, 256, 448, 448};
    unsigned long long base = 0;
    for (int i = 0; i < 8; ++i) {
        T.W1[i] = s1[i]; T.W2[i] = s2[i]; T.dst[i] = dsts[i];
        T.K[i] = Ks[i]; T.N1[i] = N1s[i]; T.N2[i] = N2s[i]; T.Kpad[i] = Kps[i];
        T.base[i] = base;
        base += (unsigned long long)Kps[i] * Nps[i];
    }
    T.total = base;   // 925,696
    k_convw<<<dim3((unsigned)((base + 255) / 256)), blk256, 0, stream>>>(T);
    k_convmisc<<<dim3((245760 + 200600 + 255) / 256), blk256, 0, stream>>>(
        cmp_W1, WT_c1, agg_W1, agg_W2, out_W, WT_a1, WT_a2, WT_o);

    // 1. hw1 GEMM (embed fused): emb-gather -> ChtA h1|t1; persists E -> EbA
    k_gemm<1><<<dim3(128, 10), blk256, 0, stream>>>(
        nullptr, nullptr, nullptr, 0, 0, x1, x2, emb,
        WT_hw1, nullptr, 320, 300, ChtA, nullptr, 600, 600, 300,
        hw1_bh, hw1_bt, 1, 2, EbA);

    // 2. hw2 GEMM (hwy1 fused): A = combine(ChtA, EbA) -> ChtB; persists X1 -> EbB
    k_gemm<2><<<dim3(128, 10), blk256, 0, stream>>>(
        ChtA, EbA, nullptr, 600, 300, nullptr, nullptr, nullptr,
        WT_hw2, nullptr, 320, 300, ChtB, nullptr, 600, 600, 300,
        hw2_bh, hw2_bt, 1, 2, EbB);

    // 3. mul+dist W1 GEMM (hwy2 fused): A = combine(ChtB, EbB) -> ChtA [NT,400];
    //    persists X2 -> EbC
    k_gemm<2><<<dim3(128, 7), blk256, 0, stream>>>(
        ChtB, EbB, nullptr, 600, 300, nullptr, nullptr, nullptr,
        WT_md, nullptr, 320, 300, ChtA, nullptr, 400, 400, 200,
        mul_b1, dist_b1, 1, 1, EbC);

    // 4. m2 + d2 dual GEMM: ChtA halves -> Pb, Qb
    k_gemm<4><<<dim3(128, 8), blk256, 0, stream>>>(
        ChtA, nullptr, nullptr, 400, 0, nullptr, nullptr, nullptr,
        WT_m2, WT_d2, 224, 200, Pb, Qb, 200, 200, 200,
        mul_b2, dist_b2, 1, 1, nullptr);

    // 5. transpose x2-halves into ChtB overlay
    int nTRb = (int)((nTR + 255) / 256);
    k_transpose2<<<dim3(nTRb, 2), blk256, 0, stream>>>(
        Pb + (size_t)NT1 * P_, PTb, Qb + (size_t)NT1 * P_, QTb);

    // 6. sim
    k_sim2<<<dim3(B_ * 16), blk256, 0, stream>>>(Pb, Qb, PTb, QTb, SIM);

    // 7. attention (merged beta+alpha) + fused EA; E = EbC
    k_av2<<<dim3(2 * NT1), blk256, 0, stream>>>(SIM, EbC, A2b, EbA);

    // 8. cmp1 GEMM: virtual K-concat {EbC, A2b, EbA(EA)} -> ChtA hidden [NT,200]
    k_gemm<3><<<dim3(128, 4), blk256, 0, stream>>>(
        EbC, A2b, EbA, 300, 0, nullptr, nullptr, nullptr,
        WT_c1, nullptr, 960, 300, ChtA, nullptr, 200, 200, 200,
        cmp_b1, cmp_b1, 1, 1, nullptr);

    // 9. cmp2 GEMM: ChtA -> Pb (Vv0)
    k_gemm<0><<<dim3(128, 4), blk256, 0, stream>>>(
        ChtA, nullptr, nullptr, 200, 0, nullptr, nullptr, nullptr,
        WT_c2, nullptr, 224, 200, Pb, nullptr, 200, 200, 200,
        cmp_b2, cmp_b2, 1, 1, nullptr);

    // 10. ch1 GEMM: Pb -> ChtB h|t [NT,400]
    k_gemm<0><<<dim3(128, 7), blk256, 0, stream>>>(
        Pb, nullptr, nullptr, 200, 0, nullptr, nullptr, nullptr,
        WT_ch1, nullptr, 224, 200, ChtB, nullptr, 400, 400, 200,
        chw1_bh, chw1_bt, 1, 2, nullptr);

    // 11. ch2 GEMM (chw1 fused): A = combine(ChtB, Pb) -> ChtA h|t; persists V1 -> Qb
    k_gemm<2><<<dim3(128, 7), blk256, 0, stream>>>(
        ChtB, Pb, nullptr, 400, 200, nullptr, nullptr, nullptr,
        WT_ch2, nullptr, 224, 200, ChtA, nullptr, 400, 400, 200,
        chw2_bh, chw2_bt, 1, 2, Qb);

    // 12. pool (chw2 fused): combine(ChtA, Qb) pooled -> POOL
    k_pool2<<<dim3(B_), blk256, 0, stream>>>(ChtA, Qb, POOL);

    // 13-15. aggregate ff + final linear: wave-per-output skinny GEMMs
    k_skinny<<<dim3(1600), blk256, 0, stream>>>(POOL, WT_a1, agg_b1, G1, B_, P_, 800, 1);
    k_skinny<<<dim3(1600), blk256, 0, stream>>>(G1, WT_a2, agg_b2, G2, B_, P_, 200, 1);
    k_skinny<<<dim3(24), blk256, 0, stream>>>(G2, WT_o, out_b, (float*)d_out, B_, 3, 200, 0);
}

// Round 11
// 367.040 us; speedup vs baseline: 1.3397x; 1.1575x over previous
//
#include <hip/hip_runtime.h>
#include <hip/hip_bf16.h>
#include <math.h>

// Problem constants
#define B_   32
#define S_   128
#define V_   30000
#define D_   300
#define P_   200
#define NT   8192         // 2*B*S token rows: x1 rows 0..4095, x2 rows 4096..8191
#define NT1  4096
// Aligned strides (64B rows)
#define LDE  320          // E-class buffers [NT,300] padded
#define LDP  256          // P-class buffers [NT,200] padded

typedef __hip_bfloat16 bf16;
typedef __attribute__((ext_vector_type(8))) __bf16 bf16x8;
typedef __attribute__((ext_vector_type(4))) float f32x4;

__device__ __forceinline__ float b2f(bf16 v) { return __bfloat162float(v); }
__device__ __forceinline__ short f2s(float v) { bf16 h = __float2bfloat16(v); return *(short*)&h; }
__device__ __forceinline__ float s2f(short s) { bf16 h; *(short*)&h = s; return __bfloat162float(h); }

// ---------------------------------------------------------------------------
// Fused weight conversion: fp32 [K][N] (two sources = N-concat or interleave)
// -> bf16 WT[Npad][Kpad], zero-padded. IL=1: phys col n -> (d=n>>1, half=n&1),
// src = half? W2[k][d] : W1[k][d]  (h/t column interleave for fused highway).
// ---------------------------------------------------------------------------
struct ConvTable {
    const float* W1[8]; const float* W2[8]; bf16* dst[8];
    int K[8], N1[8], N2[8], Kpad[8], IL[8];
    unsigned long long base[8]; unsigned long long total;
};

__global__ void k_convw(ConvTable T) {
    unsigned long long idx = (unsigned long long)blockIdx.x * 256 + threadIdx.x;
    if (idx >= T.total) return;
    int e = 0;
#pragma unroll
    for (int i = 1; i < 8; ++i) if (idx >= T.base[i]) e = i;
    unsigned long long local = idx - T.base[e];
    int Kpad = T.Kpad[e];
    int n = (int)(local / Kpad);
    int k = (int)(local - (unsigned long long)n * Kpad);
    float v = 0.f;
    if (k < T.K[e]) {
        if (T.IL[e]) {
            int d = n >> 1, half = n & 1;
            if (d < T.N1[e]) v = (half ? T.W2[e] : T.W1[e])[(size_t)k * T.N1[e] + d];
        } else {
            if (n < T.N1[e]) v = T.W1[e][(size_t)k * T.N1[e] + n];
            else if (n < T.N1[e] + T.N2[e]) v = T.W2[e][(size_t)k * T.N2[e] + (n - T.N1[e])];
        }
    }
    T.dst[e][local] = __float2bfloat16(v);
}

// ---------------------------------------------------------------------------
// Misc conversions: combined cmp_W1 (decomposed concat) + fp32 tail transposes
// ---------------------------------------------------------------------------
__global__ void k_convmisc(const float* __restrict__ Wc, bf16* __restrict__ dstc,
                           const float* __restrict__ A1w, const float* __restrict__ A2w,
                           const float* __restrict__ Ow,
                           float* __restrict__ T1, float* __restrict__ T2,
                           float* __restrict__ T3) {
    int idx = blockIdx.x * 256 + threadIdx.x;
    if (idx < 245760) {
        int n = idx / 960, k = idx - n * 960;
        int sel = k / 320, kc = k - sel * 320;
        float v = 0.f;
        if (kc < 300 && n < 200) {
            if (sel == 0)      v = Wc[(size_t)kc * 200 + n] + Wc[(size_t)(600 + kc) * 200 + n];
            else if (sel == 1) v = Wc[(size_t)(300 + kc) * 200 + n] - Wc[(size_t)(600 + kc) * 200 + n];
            else               v = Wc[(size_t)(900 + kc) * 200 + n];
        }
        dstc[idx] = __float2bfloat16(v);
    } else {
        int l = idx - 245760;
        if (l < 160000)       T1[l] = A1w[(size_t)(l % 800) * 200 + l / 800];
        else if (l < 200000)  { int m = l - 160000; T2[m] = A2w[(size_t)(m % 200) * 200 + m / 200]; }
        else if (l < 200600)  { int m = l - 200000; T3[m] = Ow[(size_t)(m % 200) * 3 + m / 200]; }
    }
}

// ---------------------------------------------------------------------------
// Skinny GEMM for tiny M (validated round 6).
// ---------------------------------------------------------------------------
__global__ __launch_bounds__(256) void k_skinny(
    const float* __restrict__ A, const float* __restrict__ WT,
    const float* __restrict__ bias, float* __restrict__ C,
    int M, int N, int K, int act) {
    int wave = (blockIdx.x * 256 + threadIdx.x) >> 6;
    int lane = threadIdx.x & 63;
    if (wave >= M * N) return;
    int m = wave / N, n = wave - m * N;
    const float4* a4 = (const float4*)(A + (size_t)m * K);
    const float4* w4 = (const float4*)(WT + (size_t)n * K);
    int K4 = K >> 2;
    float acc = 0.f;
    for (int i = lane; i < K4; i += 64) {
        float4 av = a4[i], wv = w4[i];
        acc += av.x * wv.x + av.y * wv.y + av.z * wv.z + av.w * wv.w;
    }
#pragma unroll
    for (int off = 32; off > 0; off >>= 1) acc += __shfl_down(acc, off, 64);
    if (lane == 0) {
        float v = acc + bias[n];
        if (act == 1) v = fmaxf(v, 0.f);
        C[(size_t)m * N + n] = v;
    }
}

// ---------------------------------------------------------------------------
// Fused MFMA GEMM. Tile 64(M) x 64(N), 4 waves 2x2, 32x32 each, BK=32.
// Grid: blockIdx.x = row-tile (128 ≡ 0 mod 8 XCDs -> same-row stripes share
// an XCD L2), blockIdx.y = column stripe. All strides 64B-aligned;
// full-stripe writes (pad cols written with clamped-bias garbage, never read).
// AMODE: 0 plain A [lda]; 1 embed-gather from fp32 emb (rows via tok1/tok2);
//        3 virtual 3-seg K-concat {A,A2,A3} (each [*,300] @LDE, 320-pad segs);
//        4 dual: half=blockIdx.y>>2 selects {A+200*half, WT/WT2, C/C2, bias}.
// EPI:   0 bias+act per col-segment, store Ntot phys cols (ldc >= stripes*64);
//        1 interleaved highway: col pairs (h,t) -> relu(h), sigmoid(t),
//          v = t*h+(1-t)*x; x from xbuf[ldxb] bf16, or emb (AMODE 1);
//          writes Ntot/2 logical cols at stride ldc.
// ---------------------------------------------------------------------------
#define TKP 40

template <int AMODE, int EPI>
__global__ __launch_bounds__(256) void k_gemm(
    const bf16* __restrict__ A, const bf16* __restrict__ A2,
    const bf16* __restrict__ A3, int lda,
    const int* __restrict__ tok1, const int* __restrict__ tok2,
    const float* __restrict__ emb,
    const bf16* __restrict__ WT, const bf16* __restrict__ WT2, int Kpad, int K,
    bf16* __restrict__ C, bf16* __restrict__ C2, int ldc, int Ntot, int N1,
    const float* __restrict__ bias1, const float* __restrict__ bias2,
    int act1, int act2, const bf16* __restrict__ xbuf, int ldxb)
{
    __shared__ short As[64][TKP];
    __shared__ short Bs[64][TKP];
    __shared__ short Cs[64][72];
    int tid = threadIdx.x;
    int w = tid >> 6, lane = tid & 63, quad = lane >> 4, l16 = lane & 15;
    int bm = blockIdx.x * 64;
    int half = 0, bn;
    if (AMODE == 4) { half = blockIdx.y >> 2; bn = (blockIdx.y & 3) * 64; }
    else bn = blockIdx.y * 64;
    const short* Wsh = (const short*)((AMODE == 4 && half) ? WT2 : WT);
    bf16* Cl = (AMODE == 4 && half) ? C2 : C;
    int wr = (w & 1) * 32, wc = (w >> 1) * 32;
    int ar = tid >> 2, ac = (tid & 3) * 8;

    const short* Abase = (const short*)A + (AMODE == 4 ? half * 200 : 0);
    int gm = bm + ar;
    int tok = 0;
    if (AMODE == 1) {
        tok = (gm < NT1) ? tok1[gm] : tok2[gm - NT1];
        if ((unsigned)tok >= (unsigned)V_) tok = 0;
    }

    f32x4 acc[2][2];
#pragma unroll
    for (int i = 0; i < 2; ++i)
#pragma unroll
        for (int j = 0; j < 2; ++j)
#pragma unroll
            for (int r = 0; r < 4; ++r) acc[i][j][r] = 0.f;

    short pa[8], pb[8];

    auto loadA = [&](int k0) {
        if (AMODE == 0 || AMODE == 4) {
            int k = k0 + ac;
            const short* src = Abase + (size_t)gm * lda + k;
            if (k + 8 <= K) {
                *(short4*)&pa[0] = ((const short4*)src)[0];
                *(short4*)&pa[4] = ((const short4*)src)[1];
            } else {
#pragma unroll
                for (int i = 0; i < 8; ++i) pa[i] = (k + i < K) ? src[i] : (short)0;
            }
        } else if (AMODE == 1) {
            int k = k0 + ac;
            const float* src = emb + (size_t)tok * 300 + k;
            float f[8];
            if (k + 8 <= K) {
                *(float4*)&f[0] = ((const float4*)src)[0];
                *(float4*)&f[4] = ((const float4*)src)[1];
            } else {
#pragma unroll
                for (int i = 0; i < 8; ++i) f[i] = (k + i < K) ? src[i] : 0.f;
            }
#pragma unroll
            for (int i = 0; i < 8; ++i) pa[i] = f2s(f[i]);
        } else {  // 3
            int sel = k0 / 320;                 // wave-uniform
            const short* base = (sel == 0) ? (const short*)A
                              : (sel == 1) ? (const short*)A2 : (const short*)A3;
            int k = (k0 - sel * 320) + ac;
            const short* src = base + (size_t)gm * LDE + k;
            if (k + 8 <= 300) {
                *(short4*)&pa[0] = ((const short4*)src)[0];
                *(short4*)&pa[4] = ((const short4*)src)[1];
            } else {
#pragma unroll
                for (int i = 0; i < 8; ++i) pa[i] = (k + i < 300) ? src[i] : (short)0;
            }
        }
    };
    auto loadB = [&](int k0) {
        const short* src = Wsh + (size_t)(bn + ar) * Kpad + k0 + ac;
        *(short4*)&pb[0] = ((const short4*)src)[0];
        *(short4*)&pb[4] = ((const short4*)src)[1];
    };

    loadA(0); loadB(0);
    for (int k0 = 0; k0 < Kpad; k0 += 32) {
        *(short4*)&As[ar][ac] = *(short4*)&pa[0];
        *(short4*)&As[ar][ac + 4] = *(short4*)&pa[4];
        *(short4*)&Bs[ar][ac] = *(short4*)&pb[0];
        *(short4*)&Bs[ar][ac + 4] = *(short4*)&pb[4];
        __syncthreads();
        if (k0 + 32 < Kpad) { loadA(k0 + 32); loadB(k0 + 32); }
        {
            bf16x8 a[2], b[2];
#pragma unroll
            for (int mt = 0; mt < 2; ++mt)
                a[mt] = *(const bf16x8*)&As[wr + mt * 16 + l16][quad * 8];
#pragma unroll
            for (int nt = 0; nt < 2; ++nt)
                b[nt] = *(const bf16x8*)&Bs[wc + nt * 16 + l16][quad * 8];
#pragma unroll
            for (int mt = 0; mt < 2; ++mt)
#pragma unroll
                for (int nt = 0; nt < 2; ++nt)
                    acc[mt][nt] = __builtin_amdgcn_mfma_f32_16x16x32_bf16(a[mt], b[nt], acc[mt][nt], 0, 0, 0);
        }
        __syncthreads();
    }
    // ---- epilogue stage 1: bias+act into LDS
#pragma unroll
    for (int mt = 0; mt < 2; ++mt) {
#pragma unroll
        for (int nt = 0; nt < 2; ++nt) {
            int cl = wc + nt * 16 + l16;
            int col = bn + cl;
            float bv; int act;
            if (EPI == 1) {
                int d = col >> 1;
                if (d > N1 - 1) d = N1 - 1;
                if (col & 1) { bv = bias2[d]; act = 2; }   // t: sigmoid
                else         { bv = bias1[d]; act = 1; }   // h: relu
            } else if (AMODE == 4) {
                int cc = (col < N1) ? col : (N1 - 1);
                bv = (half ? bias2 : bias1)[cc]; act = act1;
            } else {
                int cc = (col < Ntot) ? col : (Ntot - 1);
                if (cc < N1) { bv = bias1[cc]; act = act1; }
                else { bv = bias2[cc - N1]; act = act2; }
            }
#pragma unroll
            for (int r = 0; r < 4; ++r) {
                float v = acc[mt][nt][r] + bv;
                if (act == 1) v = fmaxf(v, 0.f);
                else if (act == 2) v = 1.f / (1.f + expf(-v));
                Cs[wr + mt * 16 + quad * 4 + r][cl] = f2s(v);
            }
        }
    }
    __syncthreads();
    // ---- epilogue stage 2: full-line coalesced stores
    if (EPI == 0) {
#pragma unroll
        for (int it = 0; it < 2; ++it) {
            int chunk = tid + it * 256;
            int rl = chunk >> 3;
            int c8 = (chunk & 7) * 8;
            short* dst = (short*)Cl + (size_t)(bm + rl) * ldc + bn + c8;
            *(short4*)dst = *(short4*)&Cs[rl][c8];
            *(short4*)(dst + 4) = *(short4*)&Cs[rl][c8 + 4];
        }
    } else {
        int d0 = bn >> 1;                        // output col base (32 per stripe)
#pragma unroll
        for (int it = 0; it < 2; ++it) {
            int chunk = tid + it * 256;          // 0..511
            int rl = chunk >> 3;
            int c4 = (chunk & 7) * 4;            // 4 outputs per thread
            int row = bm + rl;
            float x[4];
            if (AMODE == 1) {
                int tk = (row < NT1) ? tok1[row] : tok2[row - NT1];
                if ((unsigned)tk >= (unsigned)V_) tk = 0;
                const float* xs = emb + (size_t)tk * 300 + d0 + c4;
#pragma unroll
                for (int i = 0; i < 4; ++i) x[i] = (d0 + c4 + i < N1) ? xs[i] : 0.f;
            } else {
                const short* xs = (const short*)xbuf + (size_t)row * ldxb + d0 + c4;
#pragma unroll
                for (int i = 0; i < 4; ++i) x[i] = s2f(xs[i]);
            }
            short o[4];
#pragma unroll
            for (int i = 0; i < 4; ++i) {
                float h = s2f(Cs[rl][2 * (c4 + i)]);
                float t = s2f(Cs[rl][2 * (c4 + i) + 1]);
                o[i] = f2s(t * h + (1.f - t) * x[i]);
            }
            *(short4*)((short*)Cl + (size_t)row * ldc + d0 + c4) = *(short4*)&o[0];
        }
    }
}

// ---------------------------------------------------------------------------
// Transpose x2-halves of two [NT,*] (stride LDP) matrices into [B,P,S].
// ---------------------------------------------------------------------------
__global__ void k_transpose2(const bf16* __restrict__ srcP, bf16* __restrict__ dstP,
                             const bf16* __restrict__ srcQ, bf16* __restrict__ dstQ) {
    int idx = blockIdx.x * 256 + threadIdx.x;
    if (idx >= B_ * P_ * S_) return;
    const bf16* src = blockIdx.y ? srcQ : srcP;
    bf16* dst = blockIdx.y ? dstQ : dstP;
    int j = idx & (S_ - 1);
    int rest = idx >> 7;
    int p = rest % P_;
    int b = rest / P_;
    dst[idx] = src[((size_t)(b * S_ + j)) * LDP + p];
}

// ---------------------------------------------------------------------------
// sim kernel (validated round 7); inputs stride LDP.
// ---------------------------------------------------------------------------
__global__ __launch_bounds__(256) void k_sim2(const bf16* __restrict__ Pmat,
                                              const bf16* __restrict__ Qmat,
                                              const bf16* __restrict__ PT,
                                              const bf16* __restrict__ QT,
                                              float* __restrict__ SIM) {
    __shared__ float qp[8][P_][2];
    int blk = blockIdx.x;
    int b = blk >> 4;
    int it = blk & 15;
    int tid = threadIdx.x;
    int j = tid & 127, h = tid >> 7;
    int row0 = b * 128 + it * 8;
    for (int x = tid; x < 8 * P_; x += 256) {
        int r = x / P_, c = x - r * P_;
        qp[r][c][0] = b2f(Qmat[(size_t)(row0 + r) * LDP + c]);
        qp[r][c][1] = b2f(Pmat[(size_t)(row0 + r) * LDP + c]);
    }
    __syncthreads();
    const bf16* ptb = PT + (size_t)b * P_ * S_;
    const bf16* qtb = QT + (size_t)b * P_ * S_;
    float acc[4] = {0.f, 0.f, 0.f, 0.f};
    for (int p = 0; p < P_; ++p) {
        float v = b2f(ptb[p * S_ + j]);
        float u = b2f(qtb[p * S_ + j]);
#pragma unroll
        for (int r = 0; r < 4; ++r) {
            int i = h * 4 + r;
            float2 w = *(const float2*)&qp[i][p][0];
            float d = w.x - u;
            acc[r] += w.y * v + __builtin_amdgcn_rcpf(1.f + fabsf(d));
        }
    }
#pragma unroll
    for (int r = 0; r < 4; ++r) {
        int i = it * 8 + h * 4 + r;
        SIM[((size_t)(b * 128 + i)) * S_ + j] = acc[r];
    }
}

// ---------------------------------------------------------------------------
// Merged softmax-weighted average + fused EA=E*ATT; E/OUT/EA stride LDE.
// ---------------------------------------------------------------------------
__global__ __launch_bounds__(256) void k_av2(const float* __restrict__ SIM,
                                             const bf16* __restrict__ E,
                                             bf16* __restrict__ OUT,
                                             bf16* __restrict__ EA) {
    int blk = blockIdx.x;
    int kind = blk >> 12;
    int blk2 = blk & 4095;
    int b = blk2 >> 7, r = blk2 & 127;
    int t = threadIdx.x;
    __shared__ float w[S_];
    __shared__ float red[S_];
    float x = 0.f;
    if (t < 128) {
        x = (kind == 0) ? SIM[(size_t)blk2 * S_ + t]
                        : SIM[((size_t)b * S_ + t) * S_ + r];
        red[t] = x;
    }
    __syncthreads();
    for (int s = 64; s > 0; s >>= 1) {
        if (t < s) red[t] = fmaxf(red[t], red[t + s]);
        __syncthreads();
    }
    float mx = red[0];
    __syncthreads();
    float ex = 0.f;
    if (t < 128) { ex = expf(x - mx); red[t] = ex; }
    __syncthreads();
    for (int s = 64; s > 0; s >>= 1) {
        if (t < s) red[t] += red[t + s];
        __syncthreads();
    }
    if (t < 128) w[t] = ex / red[0];
    __syncthreads();
    if (t < 150) {
        int orow_idx = (kind == 0) ? blk2 : (NT1 + blk2);
        const bf16* Esrc = E + (kind == 0 ? (size_t)NT1 * LDE : 0) + (size_t)b * S_ * LDE;
        const unsigned short* ebase = (const unsigned short*)Esrc + 2 * t;
        float a0 = 0.f, a1 = 0.f;
        for (int s = 0; s < S_; ++s) {
            unsigned int uv = *(const unsigned int*)(ebase + (size_t)s * LDE);
            float lo = __uint_as_float(uv << 16);
            float hi = __uint_as_float(uv & 0xffff0000u);
            float ws = w[s];
            a0 += ws * lo;
            a1 += ws * hi;
        }
        unsigned int o = (unsigned int)(unsigned short)f2s(a0)
                       | ((unsigned int)(unsigned short)f2s(a1) << 16);
        *(unsigned int*)((unsigned short*)OUT + (size_t)orow_idx * LDE + 2 * t) = o;
        unsigned int ev = *(const unsigned int*)((const unsigned short*)E + (size_t)orow_idx * LDE + 2 * t);
        float e0 = __uint_as_float(ev << 16);
        float e1 = __uint_as_float(ev & 0xffff0000u);
        unsigned int o2 = (unsigned int)(unsigned short)f2s(a0 * e0)
                        | ((unsigned int)(unsigned short)f2s(a1 * e1) << 16);
        *(unsigned int*)((unsigned short*)EA + (size_t)orow_idx * LDE + 2 * t) = o2;
    }
}

// ---------------------------------------------------------------------------
// Pool: V [NT, LDP], out[b] = concat(max_i v1, max_j v2, sum_i v1, sum_j v2)
// ---------------------------------------------------------------------------
__global__ __launch_bounds__(256) void k_pool(const bf16* __restrict__ V,
                                              float* __restrict__ OUT) {
    int b = blockIdx.x;
    int c = threadIdx.x;
    if (c >= P_) return;
    const bf16* v1 = V + (size_t)(b * S_) * LDP;
    const bf16* v2 = V + (size_t)(NT1 + b * S_) * LDP;
    float mx1 = -INFINITY, mx2 = -INFINITY, s1 = 0.f, s2 = 0.f;
    for (int i = 0; i < S_; ++i) {
        float a = b2f(v1[(size_t)i * LDP + c]);
        mx1 = fmaxf(mx1, a); s1 += a;
        float bb = b2f(v2[(size_t)i * LDP + c]);
        mx2 = fmaxf(mx2, bb); s2 += bb;
    }
    float* o = OUT + (size_t)b * 4 * P_;
    o[c] = mx1; o[P_ + c] = mx2; o[2 * P_ + c] = s1; o[3 * P_ + c] = s2;
}

// Sentinel fill (diagnostic: absmax ~555 => ws_size too small)
__global__ void k_fillf(float* dst, int n, float v) {
    int i = blockIdx.x * 256 + threadIdx.x;
    if (i < n) dst[i] = v;
}

// ---------------------------------------------------------------------------
// Launch
// ---------------------------------------------------------------------------
extern "C" void kernel_launch(void* const* d_in, const int* in_sizes, int n_in,
                              void* d_out, int out_size, void* d_ws, size_t ws_size,
                              hipStream_t stream) {
    const int* x1 = (const int*)d_in[0];
    const int* x2 = (const int*)d_in[1];
    const float* emb = (const float*)d_in[2];
    const float *hw1_Wh = (const float*)d_in[3],  *hw1_bh = (const float*)d_in[4];
    const float *hw1_Wt = (const float*)d_in[5],  *hw1_bt = (const float*)d_in[6];
    const float *hw2_Wh = (const float*)d_in[7],  *hw2_bh = (const float*)d_in[8];
    const float *hw2_Wt = (const float*)d_in[9],  *hw2_bt = (const float*)d_in[10];
    const float *mul_W1 = (const float*)d_in[11], *mul_b1 = (const float*)d_in[12];
    const float *mul_W2 = (const float*)d_in[13], *mul_b2 = (const float*)d_in[14];
    const float *dist_W1 = (const float*)d_in[15], *dist_b1 = (const float*)d_in[16];
    const float *dist_W2 = (const float*)d_in[17], *dist_b2 = (const float*)d_in[18];
    const float *cmp_W1 = (const float*)d_in[19], *cmp_b1 = (const float*)d_in[20];
    const float *cmp_W2 = (const float*)d_in[21], *cmp_b2 = (const float*)d_in[22];
    const float *chw1_Wh = (const float*)d_in[23], *chw1_bh = (const float*)d_in[24];
    const float *chw1_Wt = (const float*)d_in[25], *chw1_bt = (const float*)d_in[26];
    const float *chw2_Wh = (const float*)d_in[27], *chw2_bh = (const float*)d_in[28];
    const float *chw2_Wt = (const float*)d_in[29], *chw2_bt = (const float*)d_in[30];
    const float *agg_W1 = (const float*)d_in[31], *agg_b1 = (const float*)d_in[32];
    const float *agg_W2 = (const float*)d_in[33], *agg_b2 = (const float*)d_in[34];
    const float *out_W = (const float*)d_in[35], *out_b = (const float*)d_in[36];

    // ---- Workspace layout (bf16 elems), all strides 64B-aligned ----
    const size_t nE = (size_t)NT * LDE;        // 2,621,440
    const size_t nP = (size_t)NT * LDP;        // 2,097,152
    const size_t nCht = (size_t)NT * 448;      // 3,670,016
    const size_t nTR = (size_t)B_ * P_ * S_;   //   819,200
    const size_t nWT = 1171456;
    size_t bf16_elems = 4 * nE + 2 * nP + 2 * nCht + nWT;
    size_t f32_elems = (size_t)B_ * 4 * P_ + 2 * (size_t)B_ * P_ + 200600;
    size_t need = bf16_elems * 2 + f32_elems * 4 + 64;
    if (ws_size < need) {
        k_fillf<<<dim3(1), dim3(256), 0, stream>>>((float*)d_out, B_ * 3, 555.f);
        return;
    }
    bf16* X1  = (bf16*)d_ws;            // [NT,LDE] after hwy1
    bf16* X2  = X1 + nE;                // [NT,LDE] final E
    bf16* ATT = X2 + nE;                // [NT,LDE]
    bf16* EA  = ATT + nE;               // [NT,LDE] E*ATT
    bf16* Pb  = EA + nE;                // [NT,LDP] mul proj -> Vv0
    bf16* Qb  = Pb + nP;                // [NT,LDP] dist proj -> V1
    bf16* ChtA = Qb + nP;               // [NT,448] md out / cmp hidden
    bf16* ChtB = ChtA + nCht;           // [NT,448] PT/QT/SIM overlay / V2
    bf16* WTp = ChtB + nCht;
    float* POOL = (float*)(WTp + nWT);
    float* G1 = POOL + (size_t)B_ * 4 * P_;
    float* G2 = G1 + (size_t)B_ * P_;
    float* WT_a1 = G2 + (size_t)B_ * P_;  // [200][800]
    float* WT_a2 = WT_a1 + 160000;        // [200][200]
    float* WT_o  = WT_a2 + 40000;         // [3][200]
    // overlays inside ChtB:
    bf16* PTb = ChtB;
    bf16* QTb = ChtB + nTR;
    float* SIM = (float*)(ChtB + 2 * nTR);
    bf16* V2 = ChtB;                      // reuse after av2 ([NT,LDP]: 4.2MB < 7.3MB)

    // converted-weight sub-buffers, Npad mult of 64
    bf16* WT_hw1 = WTp + 0;        // 640x320 interleaved h|t
    bf16* WT_hw2 = WTp + 204800;   // 640x320 interleaved
    bf16* WT_md  = WTp + 409600;   // 448x320 (mul_W1 | dist_W1)
    bf16* WT_m2  = WTp + 552960;   // 256x224
    bf16* WT_d2  = WTp + 610304;   // 256x224
    bf16* WT_c2  = WTp + 667648;   // 256x224
    bf16* WT_ch1 = WTp + 724992;   // 448x224 interleaved
    bf16* WT_ch2 = WTp + 825344;   // 448x224 interleaved
    bf16* WT_c1  = WTp + 925696;   // 256x960 (combined cmp_W1)

    dim3 blk256(256);

    // 0. weight conversions
    ConvTable T;
    const float* s1[8] = {hw1_Wh, hw2_Wh, mul_W1, mul_W2, dist_W2, cmp_W2, chw1_Wh, chw2_Wh};
    const float* s2[8] = {hw1_Wt, hw2_Wt, dist_W1, nullptr, nullptr, nullptr, chw1_Wt, chw2_Wt};
    bf16* dsts[8] = {WT_hw1, WT_hw2, WT_md, WT_m2, WT_d2, WT_c2, WT_ch1, WT_ch2};
    int Ks[8]  = {300, 300, 300, 200, 200, 200, 200, 200};
    int N1s[8] = {300, 300, 200, 200, 200, 200, 200, 200};
    int N2s[8] = {300, 300, 200, 0, 0, 0, 200, 200};
    int Kps[8] = {320, 320, 320, 224, 224, 224, 224, 224};
    int Nps[8] = {640, 640, 448, 256, 256, 256, 448, 448};
    int ILs[8] = {1, 1, 0, 0, 0, 0, 1, 1};
    unsigned long long base = 0;
    for (int i = 0; i < 8; ++i) {
        T.W1[i] = s1[i]; T.W2[i] = s2[i]; T.dst[i] = dsts[i];
        T.K[i] = Ks[i]; T.N1[i] = N1s[i]; T.N2[i] = N2s[i]; T.Kpad[i] = Kps[i];
        T.IL[i] = ILs[i];
        T.base[i] = base;
        base += (unsigned long long)Kps[i] * Nps[i];
    }
    T.total = base;   // 925,696
    k_convw<<<dim3((unsigned)((base + 255) / 256)), blk256, 0, stream>>>(T);
    k_convmisc<<<dim3((245760 + 200600 + 255) / 256), blk256, 0, stream>>>(
        cmp_W1, WT_c1, agg_W1, agg_W2, out_W, WT_a1, WT_a2, WT_o);

    // 1. hw1: embed-gather A, interleaved h|t, fused highway (x=emb) -> X1
    k_gemm<1, 1><<<dim3(128, 10), blk256, 0, stream>>>(
        nullptr, nullptr, nullptr, 0, x1, x2, emb,
        WT_hw1, nullptr, 320, 300, X1, nullptr, LDE, 600, 300,
        hw1_bh, hw1_bt, 1, 2, nullptr, 0);

    // 2. hw2: A=X1, fused highway (x=X1) -> X2
    k_gemm<0, 1><<<dim3(128, 10), blk256, 0, stream>>>(
        X1, nullptr, nullptr, LDE, nullptr, nullptr, nullptr,
        WT_hw2, nullptr, 320, 300, X2, nullptr, LDE, 600, 300,
        hw2_bh, hw2_bt, 1, 2, X1, LDE);

    // 3. md: A=X2 -> ChtA [NT,448] (mul hidden | dist hidden)
    k_gemm<0, 0><<<dim3(128, 7), blk256, 0, stream>>>(
        X2, nullptr, nullptr, LDE, nullptr, nullptr, nullptr,
        WT_md, nullptr, 320, 300, ChtA, nullptr, 448, 400, 200,
        mul_b1, dist_b1, 1, 1, nullptr, 0);

    // 4. m2 + d2 dual: ChtA halves -> Pb, Qb
    k_gemm<4, 0><<<dim3(128, 8), blk256, 0, stream>>>(
        ChtA, nullptr, nullptr, 448, nullptr, nullptr, nullptr,
        WT_m2, WT_d2, 224, 200, Pb, Qb, LDP, 256, 200,
        mul_b2, dist_b2, 1, 1, nullptr, 0);

    // 5. transpose x2-halves into ChtB overlay
    int nTRb = (int)((nTR + 255) / 256);
    k_transpose2<<<dim3(nTRb, 2), blk256, 0, stream>>>(
        Pb + (size_t)NT1 * LDP, PTb, Qb + (size_t)NT1 * LDP, QTb);

    // 6. sim
    k_sim2<<<dim3(B_ * 16), blk256, 0, stream>>>(Pb, Qb, PTb, QTb, SIM);

    // 7. attention (merged beta+alpha) + fused EA; E = X2
    k_av2<<<dim3(2 * NT1), blk256, 0, stream>>>(SIM, X2, ATT, EA);

    // 8. cmp1: virtual K-concat {X2, ATT, EA} -> ChtA hidden [NT,LDP-strided? 256]
    k_gemm<3, 0><<<dim3(128, 4), blk256, 0, stream>>>(
        X2, ATT, EA, LDE, nullptr, nullptr, nullptr,
        WT_c1, nullptr, 960, 300, ChtA, nullptr, LDP, 256, 200,
        cmp_b1, cmp_b1, 1, 1, nullptr, 0);

    // 9. cmp2: ChtA -> Pb (Vv0)
    k_gemm<0, 0><<<dim3(128, 4), blk256, 0, stream>>>(
        ChtA, nullptr, nullptr, LDP, nullptr, nullptr, nullptr,
        WT_c2, nullptr, 224, 200, Pb, nullptr, LDP, 256, 200,
        cmp_b2, cmp_b2, 1, 1, nullptr, 0);

    // 10. ch1: A=Pb, interleaved h|t, fused highway (x=Pb) -> Qb (V1)
    k_gemm<0, 1><<<dim3(128, 7), blk256, 0, stream>>>(
        Pb, nullptr, nullptr, LDP, nullptr, nullptr, nullptr,
        WT_ch1, nullptr, 224, 200, Qb, nullptr, LDP, 400, 200,
        chw1_bh, chw1_bt, 1, 2, Pb, LDP);

    // 11. ch2: A=Qb, fused highway (x=Qb) -> V2 (ChtB reuse)
    k_gemm<0, 1><<<dim3(128, 7), blk256, 0, stream>>>(
        Qb, nullptr, nullptr, LDP, nullptr, nullptr, nullptr,
        WT_ch2, nullptr, 224, 200, V2, nullptr, LDP, 400, 200,
        chw2_bh, chw2_bt, 1, 2, Qb, LDP);

    // 12. pool
    k_pool<<<dim3(B_), blk256, 0, stream>>>(V2, POOL);

    // 13-15. aggregate ff + final linear: wave-per-output skinny GEMMs
    k_skinny<<<dim3(1600), blk256, 0, stream>>>(POOL, WT_a1, agg_b1, G1, B_, P_, 800, 1);
    k_skinny<<<dim3(1600), blk256, 0, stream>>>(G1, WT_a2, agg_b2, G2, B_, P_, 200, 1);
    k_skinny<<<dim3(24), blk256, 0, stream>>>(G2, WT_o, out_b, (float*)d_out, B_, 3, 200, 0);
}

// Round 12
// 337.200 us; speedup vs baseline: 1.4583x; 1.0885x over previous
//
#include <hip/hip_runtime.h>
#include <hip/hip_bf16.h>
#include <math.h>

// Problem constants
#define B_   32
#define S_   128
#define V_   30000
#define D_   300
#define P_   200
#define NT   8192         // 2*B*S token rows: x1 rows 0..4095, x2 rows 4096..8191
#define NT1  4096
// Aligned strides (64B rows)
#define LDE  320          // E-class buffers [NT,300] padded
#define LDP  256          // P-class buffers [NT,200] padded

typedef __hip_bfloat16 bf16;
typedef __attribute__((ext_vector_type(8))) __bf16 bf16x8;
typedef __attribute__((ext_vector_type(4))) float f32x4;

__device__ __forceinline__ float b2f(bf16 v) { return __bfloat162float(v); }
__device__ __forceinline__ short f2s(float v) { bf16 h = __float2bfloat16(v); return *(short*)&h; }
__device__ __forceinline__ float s2f(short s) { bf16 h; *(short*)&h = s; return __bfloat162float(h); }

// ---------------------------------------------------------------------------
// Fused weight conversion: fp32 [K][N] (two sources = N-concat or interleave)
// -> bf16 WT[Npad][Kpad], zero-padded, Kpad mult of 64.
// IL=1: phys col n -> (d=n>>1, half=n&1): h/t column interleave.
// ---------------------------------------------------------------------------
struct ConvTable {
    const float* W1[8]; const float* W2[8]; bf16* dst[8];
    int K[8], N1[8], N2[8], Kpad[8], IL[8];
    unsigned long long base[8]; unsigned long long total;
};

__global__ void k_convw(ConvTable T) {
    unsigned long long idx = (unsigned long long)blockIdx.x * 256 + threadIdx.x;
    if (idx >= T.total) return;
    int e = 0;
#pragma unroll
    for (int i = 1; i < 8; ++i) if (idx >= T.base[i]) e = i;
    unsigned long long local = idx - T.base[e];
    int Kpad = T.Kpad[e];
    int n = (int)(local / Kpad);
    int k = (int)(local - (unsigned long long)n * Kpad);
    float v = 0.f;
    if (k < T.K[e]) {
        if (T.IL[e]) {
            int d = n >> 1, half = n & 1;
            if (d < T.N1[e]) v = (half ? T.W2[e] : T.W1[e])[(size_t)k * T.N1[e] + d];
        } else {
            if (n < T.N1[e]) v = T.W1[e][(size_t)k * T.N1[e] + n];
            else if (n < T.N1[e] + T.N2[e]) v = T.W2[e][(size_t)k * T.N2[e] + (n - T.N1[e])];
        }
    }
    T.dst[e][local] = __float2bfloat16(v);
}

// ---------------------------------------------------------------------------
// Misc conversions: combined cmp_W1 (decomposed concat) + fp32 tail transposes
// ---------------------------------------------------------------------------
__global__ void k_convmisc(const float* __restrict__ Wc, bf16* __restrict__ dstc,
                           const float* __restrict__ A1w, const float* __restrict__ A2w,
                           const float* __restrict__ Ow,
                           float* __restrict__ T1, float* __restrict__ T2,
                           float* __restrict__ T3) {
    int idx = blockIdx.x * 256 + threadIdx.x;
    if (idx < 245760) {
        int n = idx / 960, k = idx - n * 960;
        int sel = k / 320, kc = k - sel * 320;
        float v = 0.f;
        if (kc < 300 && n < 200) {
            if (sel == 0)      v = Wc[(size_t)kc * 200 + n] + Wc[(size_t)(600 + kc) * 200 + n];
            else if (sel == 1) v = Wc[(size_t)(300 + kc) * 200 + n] - Wc[(size_t)(600 + kc) * 200 + n];
            else               v = Wc[(size_t)(900 + kc) * 200 + n];
        }
        dstc[idx] = __float2bfloat16(v);
    } else {
        int l = idx - 245760;
        if (l < 160000)       T1[l] = A1w[(size_t)(l % 800) * 200 + l / 800];
        else if (l < 200000)  { int m = l - 160000; T2[m] = A2w[(size_t)(m % 200) * 200 + m / 200]; }
        else if (l < 200600)  { int m = l - 200000; T3[m] = Ow[(size_t)(m % 200) * 3 + m / 200]; }
    }
}

// ---------------------------------------------------------------------------
// Embedding gather: fp32 emb -> bf16 Eb [NT,LDE], zero pads. 4 cols/thread.
// ---------------------------------------------------------------------------
__global__ void k_embed(const int* __restrict__ x1, const int* __restrict__ x2,
                        const float* __restrict__ emb, bf16* __restrict__ E) {
    int idx = blockIdx.x * 256 + threadIdx.x;
    if (idx >= NT * (LDE / 4)) return;
    int r = idx / (LDE / 4);
    int c4 = (idx - r * (LDE / 4)) * 4;
    int tok = (r < NT1) ? x1[r] : x2[r - NT1];
    if ((unsigned)tok >= (unsigned)V_) tok = 0;
    short o[4];
    if (c4 + 4 <= 300) {
        float4 v = *(const float4*)(emb + (size_t)tok * 300 + c4);
        o[0] = f2s(v.x); o[1] = f2s(v.y); o[2] = f2s(v.z); o[3] = f2s(v.w);
    } else {
#pragma unroll
        for (int i = 0; i < 4; ++i) {
            int c = c4 + i;
            o[i] = f2s((c < 300) ? emb[(size_t)tok * 300 + c] : 0.f);
        }
    }
    *(short4*)((short*)E + (size_t)r * LDE + c4) = *(short4*)&o[0];
}

// ---------------------------------------------------------------------------
// Skinny GEMM for tiny M (validated round 6).
// ---------------------------------------------------------------------------
__global__ __launch_bounds__(256) void k_skinny(
    const float* __restrict__ A, const float* __restrict__ WT,
    const float* __restrict__ bias, float* __restrict__ C,
    int M, int N, int K, int act) {
    int wave = (blockIdx.x * 256 + threadIdx.x) >> 6;
    int lane = threadIdx.x & 63;
    if (wave >= M * N) return;
    int m = wave / N, n = wave - m * N;
    const float4* a4 = (const float4*)(A + (size_t)m * K);
    const float4* w4 = (const float4*)(WT + (size_t)n * K);
    int K4 = K >> 2;
    float acc = 0.f;
    for (int i = lane; i < K4; i += 64) {
        float4 av = a4[i], wv = w4[i];
        acc += av.x * wv.x + av.y * wv.y + av.z * wv.z + av.w * wv.w;
    }
#pragma unroll
    for (int off = 32; off > 0; off >>= 1) acc += __shfl_down(acc, off, 64);
    if (lane == 0) {
        float v = acc + bias[n];
        if (act == 1) v = fmaxf(v, 0.f);
        C[(size_t)m * N + n] = v;
    }
}

// ---------------------------------------------------------------------------
// Fused MFMA GEMM, BK=64. Tile 64(M) x 64(N), 4 waves 2x2, 32x32 each.
// Grid: blockIdx.x = row-tile (128 ≡ 0 mod 8 XCDs), blockIdx.y = col stripe.
// AMODE: 0 plain A [lda]; 3 virtual 3-seg K-concat {A,A2,A3} (@LDE, 320-pad);
//        4 dual: half=blockIdx.y>>2 selects {A+200*half, WT/WT2, C/C2, bias}.
// EPI:   0 bias+act, full-stripe stores; 1 interleaved highway epilogue
//        (h,t col pairs -> t*relu? no: relu(h), sigmoid(t), v=t*h+(1-t)*x).
// C-tile staged through LDS (overlaying As) for full-line stores.
// ---------------------------------------------------------------------------
template <int AMODE, int EPI>
__global__ __launch_bounds__(256) void k_gemm(
    const bf16* __restrict__ A, const bf16* __restrict__ A2,
    const bf16* __restrict__ A3, int lda,
    const bf16* __restrict__ WT, const bf16* __restrict__ WT2, int Kpad, int K,
    bf16* __restrict__ C, bf16* __restrict__ C2, int ldc, int Ntot, int N1,
    const float* __restrict__ bias1, const float* __restrict__ bias2,
    int act1, int act2, const bf16* __restrict__ xbuf, int ldxb)
{
    __shared__ short As[64][72];
    __shared__ short Bs[64][72];
    int tid = threadIdx.x;
    int w = tid >> 6, lane = tid & 63, quad = lane >> 4, l16 = lane & 15;
    int bm = blockIdx.x * 64;
    int half = 0, bn;
    if (AMODE == 4) { half = blockIdx.y >> 2; bn = (blockIdx.y & 3) * 64; }
    else bn = blockIdx.y * 64;
    const short* Wsh = (const short*)((AMODE == 4 && half) ? WT2 : WT);
    bf16* Cl = (AMODE == 4 && half) ? C2 : C;
    int wr = (w & 1) * 32, wc = (w >> 1) * 32;
    int ar = tid >> 2, ac = (tid & 3) * 16;    // stage: row 0..63, 16-k chunk

    const short* Abase = (const short*)A + (AMODE == 4 ? half * 200 : 0);
    int gm = bm + ar;

    f32x4 acc[2][2];
#pragma unroll
    for (int i = 0; i < 2; ++i)
#pragma unroll
        for (int j = 0; j < 2; ++j)
#pragma unroll
            for (int r = 0; r < 4; ++r) acc[i][j][r] = 0.f;

    short pa[16], pb[16];

    auto loadA = [&](int k0) {
        if (AMODE != 3) {
            int k = k0 + ac;
            const short* src = Abase + (size_t)gm * lda + k;
            if (k + 16 <= K) {
#pragma unroll
                for (int i = 0; i < 4; ++i) *(short4*)&pa[i * 4] = ((const short4*)src)[i];
            } else {
#pragma unroll
                for (int i = 0; i < 16; ++i) pa[i] = (k + i < K) ? src[i] : (short)0;
            }
        } else {
            int sel = k0 / 320;                 // wave-uniform (320 % 64 == 0)
            const short* base = (sel == 0) ? (const short*)A
                              : (sel == 1) ? (const short*)A2 : (const short*)A3;
            int k = (k0 - sel * 320) + ac;
            const short* src = base + (size_t)gm * LDE + k;
            if (k + 16 <= 300) {
#pragma unroll
                for (int i = 0; i < 4; ++i) *(short4*)&pa[i * 4] = ((const short4*)src)[i];
            } else {
#pragma unroll
                for (int i = 0; i < 16; ++i) pa[i] = (k + i < 300) ? src[i] : (short)0;
            }
        }
    };
    auto loadB = [&](int k0) {
        const short* src = Wsh + (size_t)(bn + ar) * Kpad + k0 + ac;
#pragma unroll
        for (int i = 0; i < 4; ++i) *(short4*)&pb[i * 4] = ((const short4*)src)[i];
    };

    loadA(0); loadB(0);
    for (int k0 = 0; k0 < Kpad; k0 += 64) {
#pragma unroll
        for (int i = 0; i < 4; ++i) {
            *(short4*)&As[ar][ac + i * 4] = *(short4*)&pa[i * 4];
            *(short4*)&Bs[ar][ac + i * 4] = *(short4*)&pb[i * 4];
        }
        __syncthreads();
        if (k0 + 64 < Kpad) { loadA(k0 + 64); loadB(k0 + 64); }
        {
            bf16x8 a[2][2], b[2][2];
#pragma unroll
            for (int mt = 0; mt < 2; ++mt)
#pragma unroll
                for (int ks = 0; ks < 2; ++ks)
                    a[mt][ks] = *(const bf16x8*)&As[wr + mt * 16 + l16][ks * 32 + quad * 8];
#pragma unroll
            for (int nt = 0; nt < 2; ++nt)
#pragma unroll
                for (int ks = 0; ks < 2; ++ks)
                    b[nt][ks] = *(const bf16x8*)&Bs[wc + nt * 16 + l16][ks * 32 + quad * 8];
#pragma unroll
            for (int mt = 0; mt < 2; ++mt)
#pragma unroll
                for (int nt = 0; nt < 2; ++nt) {
                    acc[mt][nt] = __builtin_amdgcn_mfma_f32_16x16x32_bf16(a[mt][0], b[nt][0], acc[mt][nt], 0, 0, 0);
                    acc[mt][nt] = __builtin_amdgcn_mfma_f32_16x16x32_bf16(a[mt][1], b[nt][1], acc[mt][nt], 0, 0, 0);
                }
        }
        __syncthreads();
    }
    // ---- epilogue stage 1: bias+act into LDS (reuse As as C-tile)
    short (*Cs)[72] = As;
#pragma unroll
    for (int mt = 0; mt < 2; ++mt) {
#pragma unroll
        for (int nt = 0; nt < 2; ++nt) {
            int cl = wc + nt * 16 + l16;
            int col = bn + cl;
            float bv; int act;
            if (EPI == 1) {
                int d = col >> 1;
                if (d > N1 - 1) d = N1 - 1;
                if (col & 1) { bv = bias2[d]; act = 2; }   // t: sigmoid
                else         { bv = bias1[d]; act = 1; }   // h: relu
            } else if (AMODE == 4) {
                int cc = (col < N1) ? col : (N1 - 1);
                bv = (half ? bias2 : bias1)[cc]; act = act1;
            } else {
                int cc = (col < Ntot) ? col : (Ntot - 1);
                if (cc < N1) { bv = bias1[cc]; act = act1; }
                else { bv = bias2[cc - N1]; act = act2; }
            }
#pragma unroll
            for (int r = 0; r < 4; ++r) {
                float v = acc[mt][nt][r] + bv;
                if (act == 1) v = fmaxf(v, 0.f);
                else if (act == 2) v = 1.f / (1.f + expf(-v));
                Cs[wr + mt * 16 + quad * 4 + r][cl] = f2s(v);
            }
        }
    }
    __syncthreads();
    // ---- epilogue stage 2: full-line coalesced stores
    if (EPI == 0) {
#pragma unroll
        for (int it = 0; it < 2; ++it) {
            int chunk = tid + it * 256;
            int rl = chunk >> 3;
            int c8 = (chunk & 7) * 8;
            short* dst = (short*)Cl + (size_t)(bm + rl) * ldc + bn + c8;
            *(short4*)dst = *(short4*)&Cs[rl][c8];
            *(short4*)(dst + 4) = *(short4*)&Cs[rl][c8 + 4];
        }
    } else {
        int d0 = bn >> 1;                        // 32 output cols per stripe
#pragma unroll
        for (int it = 0; it < 2; ++it) {
            int chunk = tid + it * 256;          // 0..511
            int rl = chunk >> 3;
            int c4 = (chunk & 7) * 4;
            int row = bm + rl;
            const short* xs = (const short*)xbuf + (size_t)row * ldxb + d0 + c4;
            short o[4];
#pragma unroll
            for (int i = 0; i < 4; ++i) {
                float h = s2f(Cs[rl][2 * (c4 + i)]);
                float t = s2f(Cs[rl][2 * (c4 + i) + 1]);
                o[i] = f2s(t * h + (1.f - t) * s2f(xs[i]));
            }
            *(short4*)((short*)Cl + (size_t)row * ldc + d0 + c4) = *(short4*)&o[0];
        }
    }
}

// ---------------------------------------------------------------------------
// Transpose x2-halves of two [NT,*] (stride LDP) matrices into [B,P,S].
// ---------------------------------------------------------------------------
__global__ void k_transpose2(const bf16* __restrict__ srcP, bf16* __restrict__ dstP,
                             const bf16* __restrict__ srcQ, bf16* __restrict__ dstQ) {
    int idx = blockIdx.x * 256 + threadIdx.x;
    if (idx >= B_ * P_ * S_) return;
    const bf16* src = blockIdx.y ? srcQ : srcP;
    bf16* dst = blockIdx.y ? dstQ : dstP;
    int j = idx & (S_ - 1);
    int rest = idx >> 7;
    int p = rest % P_;
    int b = rest / P_;
    dst[idx] = src[((size_t)(b * S_ + j)) * LDP + p];
}

// ---------------------------------------------------------------------------
// sim kernel (validated round 7); inputs stride LDP.
// ---------------------------------------------------------------------------
__global__ __launch_bounds__(256) void k_sim2(const bf16* __restrict__ Pmat,
                                              const bf16* __restrict__ Qmat,
                                              const bf16* __restrict__ PT,
                                              const bf16* __restrict__ QT,
                                              float* __restrict__ SIM) {
    __shared__ float qp[8][P_][2];
    int blk = blockIdx.x;
    int b = blk >> 4;
    int it = blk & 15;
    int tid = threadIdx.x;
    int j = tid & 127, h = tid >> 7;
    int row0 = b * 128 + it * 8;
    for (int x = tid; x < 8 * P_; x += 256) {
        int r = x / P_, c = x - r * P_;
        qp[r][c][0] = b2f(Qmat[(size_t)(row0 + r) * LDP + c]);
        qp[r][c][1] = b2f(Pmat[(size_t)(row0 + r) * LDP + c]);
    }
    __syncthreads();
    const bf16* ptb = PT + (size_t)b * P_ * S_;
    const bf16* qtb = QT + (size_t)b * P_ * S_;
    float acc[4] = {0.f, 0.f, 0.f, 0.f};
    for (int p = 0; p < P_; ++p) {
        float v = b2f(ptb[p * S_ + j]);
        float u = b2f(qtb[p * S_ + j]);
#pragma unroll
        for (int r = 0; r < 4; ++r) {
            int i = h * 4 + r;
            float2 w = *(const float2*)&qp[i][p][0];
            float d = w.x - u;
            acc[r] += w.y * v + __builtin_amdgcn_rcpf(1.f + fabsf(d));
        }
    }
#pragma unroll
    for (int r = 0; r < 4; ++r) {
        int i = it * 8 + h * 4 + r;
        SIM[((size_t)(b * 128 + i)) * S_ + j] = acc[r];
    }
}

// ---------------------------------------------------------------------------
// Merged softmax-weighted average + fused EA=E*ATT; E/OUT/EA stride LDE.
// ---------------------------------------------------------------------------
__global__ __launch_bounds__(256) void k_av2(const float* __restrict__ SIM,
                                             const bf16* __restrict__ E,
                                             bf16* __restrict__ OUT,
                                             bf16* __restrict__ EA) {
    int blk = blockIdx.x;
    int kind = blk >> 12;
    int blk2 = blk & 4095;
    int b = blk2 >> 7, r = blk2 & 127;
    int t = threadIdx.x;
    __shared__ float w[S_];
    __shared__ float red[S_];
    float x = 0.f;
    if (t < 128) {
        x = (kind == 0) ? SIM[(size_t)blk2 * S_ + t]
                        : SIM[((size_t)b * S_ + t) * S_ + r];
        red[t] = x;
    }
    __syncthreads();
    for (int s = 64; s > 0; s >>= 1) {
        if (t < s) red[t] = fmaxf(red[t], red[t + s]);
        __syncthreads();
    }
    float mx = red[0];
    __syncthreads();
    float ex = 0.f;
    if (t < 128) { ex = expf(x - mx); red[t] = ex; }
    __syncthreads();
    for (int s = 64; s > 0; s >>= 1) {
        if (t < s) red[t] += red[t + s];
        __syncthreads();
    }
    if (t < 128) w[t] = ex / red[0];
    __syncthreads();
    if (t < 150) {
        int orow_idx = (kind == 0) ? blk2 : (NT1 + blk2);
        const bf16* Esrc = E + (kind == 0 ? (size_t)NT1 * LDE : 0) + (size_t)b * S_ * LDE;
        const unsigned short* ebase = (const unsigned short*)Esrc + 2 * t;
        float a0 = 0.f, a1 = 0.f;
        for (int s = 0; s < S_; ++s) {
            unsigned int uv = *(const unsigned int*)(ebase + (size_t)s * LDE);
            float lo = __uint_as_float(uv << 16);
            float hi = __uint_as_float(uv & 0xffff0000u);
            float ws = w[s];
            a0 += ws * lo;
            a1 += ws * hi;
        }
        unsigned int o = (unsigned int)(unsigned short)f2s(a0)
                       | ((unsigned int)(unsigned short)f2s(a1) << 16);
        *(unsigned int*)((unsigned short*)OUT + (size_t)orow_idx * LDE + 2 * t) = o;
        unsigned int ev = *(const unsigned int*)((const unsigned short*)E + (size_t)orow_idx * LDE + 2 * t);
        float e0 = __uint_as_float(ev << 16);
        float e1 = __uint_as_float(ev & 0xffff0000u);
        unsigned int o2 = (unsigned int)(unsigned short)f2s(a0 * e0)
                        | ((unsigned int)(unsigned short)f2s(a1 * e1) << 16);
        *(unsigned int*)((unsigned short*)EA + (size_t)orow_idx * LDE + 2 * t) = o2;
    }
}

// ---------------------------------------------------------------------------
// Pool: V [NT, LDP]
// ---------------------------------------------------------------------------
__global__ __launch_bounds__(256) void k_pool(const bf16* __restrict__ V,
                                              float* __restrict__ OUT) {
    int b = blockIdx.x;
    int c = threadIdx.x;
    if (c >= P_) return;
    const bf16* v1 = V + (size_t)(b * S_) * LDP;
    const bf16* v2 = V + (size_t)(NT1 + b * S_) * LDP;
    float mx1 = -INFINITY, mx2 = -INFINITY, s1 = 0.f, s2 = 0.f;
    for (int i = 0; i < S_; ++i) {
        float a = b2f(v1[(size_t)i * LDP + c]);
        mx1 = fmaxf(mx1, a); s1 += a;
        float bb = b2f(v2[(size_t)i * LDP + c]);
        mx2 = fmaxf(mx2, bb); s2 += bb;
    }
    float* o = OUT + (size_t)b * 4 * P_;
    o[c] = mx1; o[P_ + c] = mx2; o[2 * P_ + c] = s1; o[3 * P_ + c] = s2;
}

// Sentinel fill (diagnostic: absmax ~555 => ws_size too small)
__global__ void k_fillf(float* dst, int n, float v) {
    int i = blockIdx.x * 256 + threadIdx.x;
    if (i < n) dst[i] = v;
}

// ---------------------------------------------------------------------------
// Launch
// ---------------------------------------------------------------------------
extern "C" void kernel_launch(void* const* d_in, const int* in_sizes, int n_in,
                              void* d_out, int out_size, void* d_ws, size_t ws_size,
                              hipStream_t stream) {
    const int* x1 = (const int*)d_in[0];
    const int* x2 = (const int*)d_in[1];
    const float* emb = (const float*)d_in[2];
    const float *hw1_Wh = (const float*)d_in[3],  *hw1_bh = (const float*)d_in[4];
    const float *hw1_Wt = (const float*)d_in[5],  *hw1_bt = (const float*)d_in[6];
    const float *hw2_Wh = (const float*)d_in[7],  *hw2_bh = (const float*)d_in[8];
    const float *hw2_Wt = (const float*)d_in[9],  *hw2_bt = (const float*)d_in[10];
    const float *mul_W1 = (const float*)d_in[11], *mul_b1 = (const float*)d_in[12];
    const float *mul_W2 = (const float*)d_in[13], *mul_b2 = (const float*)d_in[14];
    const float *dist_W1 = (const float*)d_in[15], *dist_b1 = (const float*)d_in[16];
    const float *dist_W2 = (const float*)d_in[17], *dist_b2 = (const float*)d_in[18];
    const float *cmp_W1 = (const float*)d_in[19], *cmp_b1 = (const float*)d_in[20];
    const float *cmp_W2 = (const float*)d_in[21], *cmp_b2 = (const float*)d_in[22];
    const float *chw1_Wh = (const float*)d_in[23], *chw1_bh = (const float*)d_in[24];
    const float *chw1_Wt = (const float*)d_in[25], *chw1_bt = (const float*)d_in[26];
    const float *chw2_Wh = (const float*)d_in[27], *chw2_bh = (const float*)d_in[28];
    const float *chw2_Wt = (const float*)d_in[29], *chw2_bt = (const float*)d_in[30];
    const float *agg_W1 = (const float*)d_in[31], *agg_b1 = (const float*)d_in[32];
    const float *agg_W2 = (const float*)d_in[33], *agg_b2 = (const float*)d_in[34];
    const float *out_W = (const float*)d_in[35], *out_b = (const float*)d_in[36];

    // ---- Workspace layout (bf16 elems), all strides 64B-aligned ----
    const size_t nE = (size_t)NT * LDE;        // 2,621,440
    const size_t nP = (size_t)NT * LDP;        // 2,097,152
    const size_t nCht = (size_t)NT * 448;      // 3,670,016
    const size_t nTR = (size_t)B_ * P_ * S_;   //   819,200
    const size_t nWT = 1224704;                // converted bf16 weights
    size_t bf16_elems = 4 * nE + 2 * nP + 2 * nCht + nWT;
    size_t f32_elems = (size_t)B_ * 4 * P_ + 2 * (size_t)B_ * P_ + 200600;
    size_t need = bf16_elems * 2 + f32_elems * 4 + 64;
    if (ws_size < need) {
        k_fillf<<<dim3(1), dim3(256), 0, stream>>>((float*)d_out, B_ * 3, 555.f);
        return;
    }
    bf16* Eb  = (bf16*)d_ws;            // [NT,LDE] embed; later ATT (dead after hw1)
    bf16* X1  = Eb + nE;                // [NT,LDE]
    bf16* X2  = X1 + nE;                // [NT,LDE] final E
    bf16* EA  = X2 + nE;                // [NT,LDE] E*ATT
    bf16* Pb  = EA + nE;                // [NT,LDP]
    bf16* Qb  = Pb + nP;                // [NT,LDP]
    bf16* ChtA = Qb + nP;               // [NT,448]
    bf16* ChtB = ChtA + nCht;           // [NT,448] PT/QT/SIM overlay / V2
    bf16* WTp = ChtB + nCht;
    float* POOL = (float*)(WTp + nWT);
    float* G1 = POOL + (size_t)B_ * 4 * P_;
    float* G2 = G1 + (size_t)B_ * P_;
    float* WT_a1 = G2 + (size_t)B_ * P_;  // [200][800]
    float* WT_a2 = WT_a1 + 160000;        // [200][200]
    float* WT_o  = WT_a2 + 40000;         // [3][200]
    bf16* ATT = Eb;                       // overlay: Eb dead after hw1
    // overlays inside ChtB:
    bf16* PTb = ChtB;
    bf16* QTb = ChtB + nTR;
    float* SIM = (float*)(ChtB + 2 * nTR);
    bf16* V2 = ChtB;                      // reuse after av2

    // converted-weight sub-buffers, Kpad mult of 64
    bf16* WT_hw1 = WTp + 0;        // 640x320 interleaved h|t
    bf16* WT_hw2 = WTp + 204800;   // 640x320 interleaved
    bf16* WT_md  = WTp + 409600;   // 448x320 (mul_W1 | dist_W1)
    bf16* WT_m2  = WTp + 552960;   // 256x256
    bf16* WT_d2  = WTp + 618496;   // 256x256
    bf16* WT_c2  = WTp + 684032;   // 256x256
    bf16* WT_ch1 = WTp + 749568;   // 448x256 interleaved
    bf16* WT_ch2 = WTp + 864256;   // 448x256 interleaved
    bf16* WT_c1  = WTp + 978944;   // 256x960 (combined cmp_W1)

    dim3 blk256(256);

    // 0. weight conversions
    ConvTable T;
    const float* s1[8] = {hw1_Wh, hw2_Wh, mul_W1, mul_W2, dist_W2, cmp_W2, chw1_Wh, chw2_Wh};
    const float* s2[8] = {hw1_Wt, hw2_Wt, dist_W1, nullptr, nullptr, nullptr, chw1_Wt, chw2_Wt};
    bf16* dsts[8] = {WT_hw1, WT_hw2, WT_md, WT_m2, WT_d2, WT_c2, WT_ch1, WT_ch2};
    int Ks[8]  = {300, 300, 300, 200, 200, 200, 200, 200};
    int N1s[8] = {300, 300, 200, 200, 200, 200, 200, 200};
    int N2s[8] = {300, 300, 200, 0, 0, 0, 200, 200};
    int Kps[8] = {320, 320, 320, 256, 256, 256, 256, 256};
    int Nps[8] = {640, 640, 448, 256, 256, 256, 448, 448};
    int ILs[8] = {1, 1, 0, 0, 0, 0, 1, 1};
    unsigned long long base = 0;
    for (int i = 0; i < 8; ++i) {
        T.W1[i] = s1[i]; T.W2[i] = s2[i]; T.dst[i] = dsts[i];
        T.K[i] = Ks[i]; T.N1[i] = N1s[i]; T.N2[i] = N2s[i]; T.Kpad[i] = Kps[i];
        T.IL[i] = ILs[i];
        T.base[i] = base;
        base += (unsigned long long)Kps[i] * Nps[i];
    }
    T.total = base;   // 978,944
    k_convw<<<dim3((unsigned)((base + 255) / 256)), blk256, 0, stream>>>(T);
    k_convmisc<<<dim3((245760 + 200600 + 255) / 256), blk256, 0, stream>>>(
        cmp_W1, WT_c1, agg_W1, agg_W2, out_W, WT_a1, WT_a2, WT_o);

    // 1. embed gather -> Eb
    k_embed<<<dim3((NT * (LDE / 4) + 255) / 256), blk256, 0, stream>>>(x1, x2, emb, Eb);

    // 2. hw1: A=Eb, interleaved h|t, fused highway (x=Eb) -> X1
    k_gemm<0, 1><<<dim3(128, 10), blk256, 0, stream>>>(
        Eb, nullptr, nullptr, LDE,
        WT_hw1, nullptr, 320, 300, X1, nullptr, LDE, 600, 300,
        hw1_bh, hw1_bt, 1, 2, Eb, LDE);

    // 3. hw2: A=X1, fused highway (x=X1) -> X2
    k_gemm<0, 1><<<dim3(128, 10), blk256, 0, stream>>>(
        X1, nullptr, nullptr, LDE,
        WT_hw2, nullptr, 320, 300, X2, nullptr, LDE, 600, 300,
        hw2_bh, hw2_bt, 1, 2, X1, LDE);

    // 4. md: A=X2 -> ChtA [NT,448] (mul hidden | dist hidden)
    k_gemm<0, 0><<<dim3(128, 7), blk256, 0, stream>>>(
        X2, nullptr, nullptr, LDE,
        WT_md, nullptr, 320, 300, ChtA, nullptr, 448, 400, 200,
        mul_b1, dist_b1, 1, 1, nullptr, 0);

    // 5. m2 + d2 dual: ChtA halves -> Pb, Qb
    k_gemm<4, 0><<<dim3(128, 8), blk256, 0, stream>>>(
        ChtA, nullptr, nullptr, 448,
        WT_m2, WT_d2, 256, 200, Pb, Qb, LDP, 256, 200,
        mul_b2, dist_b2, 1, 1, nullptr, 0);

    // 6. transpose x2-halves into ChtB overlay
    int nTRb = (int)((nTR + 255) / 256);
    k_transpose2<<<dim3(nTRb, 2), blk256, 0, stream>>>(
        Pb + (size_t)NT1 * LDP, PTb, Qb + (size_t)NT1 * LDP, QTb);

    // 7. sim
    k_sim2<<<dim3(B_ * 16), blk256, 0, stream>>>(Pb, Qb, PTb, QTb, SIM);

    // 8. attention (merged beta+alpha) + fused EA; E = X2; ATT overlays Eb
    k_av2<<<dim3(2 * NT1), blk256, 0, stream>>>(SIM, X2, ATT, EA);

    // 9. cmp1: virtual K-concat {X2, ATT, EA} -> ChtA hidden [NT,LDP]
    k_gemm<3, 0><<<dim3(128, 4), blk256, 0, stream>>>(
        X2, ATT, EA, LDE,
        WT_c1, nullptr, 960, 300, ChtA, nullptr, LDP, 200, 200,
        cmp_b1, cmp_b1, 1, 1, nullptr, 0);

    // 10. cmp2: ChtA -> Pb (Vv0)
    k_gemm<0, 0><<<dim3(128, 4), blk256, 0, stream>>>(
        ChtA, nullptr, nullptr, LDP,
        WT_c2, nullptr, 256, 200, Pb, nullptr, LDP, 200, 200,
        cmp_b2, cmp_b2, 1, 1, nullptr, 0);

    // 11. ch1: A=Pb, interleaved h|t, fused highway (x=Pb) -> Qb (V1)
    k_gemm<0, 1><<<dim3(128, 7), blk256, 0, stream>>>(
        Pb, nullptr, nullptr, LDP,
        WT_ch1, nullptr, 256, 200, Qb, nullptr, LDP, 400, 200,
        chw1_bh, chw1_bt, 1, 2, Pb, LDP);

    // 12. ch2: A=Qb, fused highway (x=Qb) -> V2 (ChtB reuse)
    k_gemm<0, 1><<<dim3(128, 7), blk256, 0, stream>>>(
        Qb, nullptr, nullptr, LDP,
        WT_ch2, nullptr, 256, 200, V2, nullptr, LDP, 400, 200,
        chw2_bh, chw2_bt, 1, 2, Qb, LDP);

    // 13. pool
    k_pool<<<dim3(B_), blk256, 0, stream>>>(V2, POOL);

    // 14-16. aggregate ff + final linear: wave-per-output skinny GEMMs
    k_skinny<<<dim3(1600), blk256, 0, stream>>>(POOL, WT_a1, agg_b1, G1, B_, P_, 800, 1);
    k_skinny<<<dim3(1600), blk256, 0, stream>>>(G1, WT_a2, agg_b2, G2, B_, P_, 200, 1);
    k_skinny<<<dim3(24), blk256, 0, stream>>>(G2, WT_o, out_b, (float*)d_out, B_, 3, 200, 0);
}

// Round 13
// 318.325 us; speedup vs baseline: 1.5448x; 1.0593x over previous
//
#include <hip/hip_runtime.h>
#include <hip/hip_bf16.h>
#include <math.h>

// Problem constants
#define B_   32
#define S_   128
#define V_   30000
#define D_   300
#define P_   200
#define NT   8192         // 2*B*S token rows: x1 rows 0..4095, x2 rows 4096..8191
#define NT1  4096
// Aligned strides (64B rows)
#define LDE  320          // E-class buffers [NT,300] padded
#define LDP  256          // P-class buffers [NT,200] padded

typedef __hip_bfloat16 bf16;
typedef __attribute__((ext_vector_type(8))) __bf16 bf16x8;
typedef __attribute__((ext_vector_type(4))) float f32x4;

__device__ __forceinline__ float b2f(bf16 v) { return __bfloat162float(v); }
__device__ __forceinline__ short f2s(float v) { bf16 h = __float2bfloat16(v); return *(short*)&h; }
__device__ __forceinline__ float s2f(short s) { bf16 h; *(short*)&h = s; return __bfloat162float(h); }

// ---------------------------------------------------------------------------
// Fused weight conversion: fp32 [K][N] (two sources = N-concat or interleave)
// -> bf16 WT[Npad][Kpad], zero-padded, Kpad mult of 64.
// IL=1: phys col n -> (d=n>>1, half=n&1): h/t column interleave.
// ---------------------------------------------------------------------------
struct ConvTable {
    const float* W1[8]; const float* W2[8]; bf16* dst[8];
    int K[8], N1[8], N2[8], Kpad[8], IL[8];
    unsigned long long base[8]; unsigned long long total;
};

__global__ void k_convw(ConvTable T) {
    unsigned long long idx = (unsigned long long)blockIdx.x * 256 + threadIdx.x;
    if (idx >= T.total) return;
    int e = 0;
#pragma unroll
    for (int i = 1; i < 8; ++i) if (idx >= T.base[i]) e = i;
    unsigned long long local = idx - T.base[e];
    int Kpad = T.Kpad[e];
    int n = (int)(local / Kpad);
    int k = (int)(local - (unsigned long long)n * Kpad);
    float v = 0.f;
    if (k < T.K[e]) {
        if (T.IL[e]) {
            int d = n >> 1, half = n & 1;
            if (d < T.N1[e]) v = (half ? T.W2[e] : T.W1[e])[(size_t)k * T.N1[e] + d];
        } else {
            if (n < T.N1[e]) v = T.W1[e][(size_t)k * T.N1[e] + n];
            else if (n < T.N1[e] + T.N2[e]) v = T.W2[e][(size_t)k * T.N2[e] + (n - T.N1[e])];
        }
    }
    T.dst[e][local] = __float2bfloat16(v);
}

// ---------------------------------------------------------------------------
// Misc conversions: combined cmp_W1 (decomposed concat) + fp32 tail transposes
// ---------------------------------------------------------------------------
__global__ void k_convmisc(const float* __restrict__ Wc, bf16* __restrict__ dstc,
                           const float* __restrict__ A1w, const float* __restrict__ A2w,
                           const float* __restrict__ Ow,
                           float* __restrict__ T1, float* __restrict__ T2,
                           float* __restrict__ T3) {
    int idx = blockIdx.x * 256 + threadIdx.x;
    if (idx < 245760) {
        int n = idx / 960, k = idx - n * 960;
        int sel = k / 320, kc = k - sel * 320;
        float v = 0.f;
        if (kc < 300 && n < 200) {
            if (sel == 0)      v = Wc[(size_t)kc * 200 + n] + Wc[(size_t)(600 + kc) * 200 + n];
            else if (sel == 1) v = Wc[(size_t)(300 + kc) * 200 + n] - Wc[(size_t)(600 + kc) * 200 + n];
            else               v = Wc[(size_t)(900 + kc) * 200 + n];
        }
        dstc[idx] = __float2bfloat16(v);
    } else {
        int l = idx - 245760;
        if (l < 160000)       T1[l] = A1w[(size_t)(l % 800) * 200 + l / 800];
        else if (l < 200000)  { int m = l - 160000; T2[m] = A2w[(size_t)(m % 200) * 200 + m / 200]; }
        else if (l < 200600)  { int m = l - 200000; T3[m] = Ow[(size_t)(m % 200) * 3 + m / 200]; }
    }
}

// ---------------------------------------------------------------------------
// Embedding gather: fp32 emb -> bf16 Eb [NT,LDE], zero pads. 4 cols/thread.
// ---------------------------------------------------------------------------
__global__ void k_embed(const int* __restrict__ x1, const int* __restrict__ x2,
                        const float* __restrict__ emb, bf16* __restrict__ E) {
    int idx = blockIdx.x * 256 + threadIdx.x;
    if (idx >= NT * (LDE / 4)) return;
    int r = idx / (LDE / 4);
    int c4 = (idx - r * (LDE / 4)) * 4;
    int tok = (r < NT1) ? x1[r] : x2[r - NT1];
    if ((unsigned)tok >= (unsigned)V_) tok = 0;
    short o[4];
    if (c4 + 4 <= 300) {
        float4 v = *(const float4*)(emb + (size_t)tok * 300 + c4);
        o[0] = f2s(v.x); o[1] = f2s(v.y); o[2] = f2s(v.z); o[3] = f2s(v.w);
    } else {
#pragma unroll
        for (int i = 0; i < 4; ++i) {
            int c = c4 + i;
            o[i] = f2s((c < 300) ? emb[(size_t)tok * 300 + c] : 0.f);
        }
    }
    *(short4*)((short*)E + (size_t)r * LDE + c4) = *(short4*)&o[0];
}

// ---------------------------------------------------------------------------
// Skinny GEMM for tiny M (validated round 6).
// ---------------------------------------------------------------------------
__global__ __launch_bounds__(256) void k_skinny(
    const float* __restrict__ A, const float* __restrict__ WT,
    const float* __restrict__ bias, float* __restrict__ C,
    int M, int N, int K, int act) {
    int wave = (blockIdx.x * 256 + threadIdx.x) >> 6;
    int lane = threadIdx.x & 63;
    if (wave >= M * N) return;
    int m = wave / N, n = wave - m * N;
    const float4* a4 = (const float4*)(A + (size_t)m * K);
    const float4* w4 = (const float4*)(WT + (size_t)n * K);
    int K4 = K >> 2;
    float acc = 0.f;
    for (int i = lane; i < K4; i += 64) {
        float4 av = a4[i], wv = w4[i];
        acc += av.x * wv.x + av.y * wv.y + av.z * wv.z + av.w * wv.w;
    }
#pragma unroll
    for (int off = 32; off > 0; off >>= 1) acc += __shfl_down(acc, off, 64);
    if (lane == 0) {
        float v = acc + bias[n];
        if (act == 1) v = fmaxf(v, 0.f);
        C[(size_t)m * N + n] = v;
    }
}

// ---------------------------------------------------------------------------
// Fused MFMA GEMM, BK=64. Tile 64(M) x 64(N), 4 waves 2x2, 32x32 each.
// (validated round 12). Grid: x = row-tile (XCD-local), y = col stripe.
// ---------------------------------------------------------------------------
template <int AMODE, int EPI>
__global__ __launch_bounds__(256) void k_gemm(
    const bf16* __restrict__ A, const bf16* __restrict__ A2,
    const bf16* __restrict__ A3, int lda,
    const bf16* __restrict__ WT, const bf16* __restrict__ WT2, int Kpad, int K,
    bf16* __restrict__ C, bf16* __restrict__ C2, int ldc, int Ntot, int N1,
    const float* __restrict__ bias1, const float* __restrict__ bias2,
    int act1, int act2, const bf16* __restrict__ xbuf, int ldxb)
{
    __shared__ short As[64][72];
    __shared__ short Bs[64][72];
    int tid = threadIdx.x;
    int w = tid >> 6, lane = tid & 63, quad = lane >> 4, l16 = lane & 15;
    int bm = blockIdx.x * 64;
    int half = 0, bn;
    if (AMODE == 4) { half = blockIdx.y >> 2; bn = (blockIdx.y & 3) * 64; }
    else bn = blockIdx.y * 64;
    const short* Wsh = (const short*)((AMODE == 4 && half) ? WT2 : WT);
    bf16* Cl = (AMODE == 4 && half) ? C2 : C;
    int wr = (w & 1) * 32, wc = (w >> 1) * 32;
    int ar = tid >> 2, ac = (tid & 3) * 16;

    const short* Abase = (const short*)A + (AMODE == 4 ? half * 200 : 0);
    int gm = bm + ar;

    f32x4 acc[2][2];
#pragma unroll
    for (int i = 0; i < 2; ++i)
#pragma unroll
        for (int j = 0; j < 2; ++j)
#pragma unroll
            for (int r = 0; r < 4; ++r) acc[i][j][r] = 0.f;

    short pa[16], pb[16];

    auto loadA = [&](int k0) {
        if (AMODE != 3) {
            int k = k0 + ac;
            const short* src = Abase + (size_t)gm * lda + k;
            if (k + 16 <= K) {
#pragma unroll
                for (int i = 0; i < 4; ++i) *(short4*)&pa[i * 4] = ((const short4*)src)[i];
            } else {
#pragma unroll
                for (int i = 0; i < 16; ++i) pa[i] = (k + i < K) ? src[i] : (short)0;
            }
        } else {
            int sel = k0 / 320;                 // wave-uniform (320 % 64 == 0)
            const short* base = (sel == 0) ? (const short*)A
                              : (sel == 1) ? (const short*)A2 : (const short*)A3;
            int k = (k0 - sel * 320) + ac;
            const short* src = base + (size_t)gm * LDE + k;
            if (k + 16 <= 300) {
#pragma unroll
                for (int i = 0; i < 4; ++i) *(short4*)&pa[i * 4] = ((const short4*)src)[i];
            } else {
#pragma unroll
                for (int i = 0; i < 16; ++i) pa[i] = (k + i < 300) ? src[i] : (short)0;
            }
        }
    };
    auto loadB = [&](int k0) {
        const short* src = Wsh + (size_t)(bn + ar) * Kpad + k0 + ac;
#pragma unroll
        for (int i = 0; i < 4; ++i) *(short4*)&pb[i * 4] = ((const short4*)src)[i];
    };

    loadA(0); loadB(0);
    for (int k0 = 0; k0 < Kpad; k0 += 64) {
#pragma unroll
        for (int i = 0; i < 4; ++i) {
            *(short4*)&As[ar][ac + i * 4] = *(short4*)&pa[i * 4];
            *(short4*)&Bs[ar][ac + i * 4] = *(short4*)&pb[i * 4];
        }
        __syncthreads();
        if (k0 + 64 < Kpad) { loadA(k0 + 64); loadB(k0 + 64); }
        {
            bf16x8 a[2][2], b[2][2];
#pragma unroll
            for (int mt = 0; mt < 2; ++mt)
#pragma unroll
                for (int ks = 0; ks < 2; ++ks)
                    a[mt][ks] = *(const bf16x8*)&As[wr + mt * 16 + l16][ks * 32 + quad * 8];
#pragma unroll
            for (int nt = 0; nt < 2; ++nt)
#pragma unroll
                for (int ks = 0; ks < 2; ++ks)
                    b[nt][ks] = *(const bf16x8*)&Bs[wc + nt * 16 + l16][ks * 32 + quad * 8];
#pragma unroll
            for (int mt = 0; mt < 2; ++mt)
#pragma unroll
                for (int nt = 0; nt < 2; ++nt) {
                    acc[mt][nt] = __builtin_amdgcn_mfma_f32_16x16x32_bf16(a[mt][0], b[nt][0], acc[mt][nt], 0, 0, 0);
                    acc[mt][nt] = __builtin_amdgcn_mfma_f32_16x16x32_bf16(a[mt][1], b[nt][1], acc[mt][nt], 0, 0, 0);
                }
        }
        __syncthreads();
    }
    short (*Cs)[72] = As;
#pragma unroll
    for (int mt = 0; mt < 2; ++mt) {
#pragma unroll
        for (int nt = 0; nt < 2; ++nt) {
            int cl = wc + nt * 16 + l16;
            int col = bn + cl;
            float bv; int act;
            if (EPI == 1) {
                int d = col >> 1;
                if (d > N1 - 1) d = N1 - 1;
                if (col & 1) { bv = bias2[d]; act = 2; }   // t: sigmoid
                else         { bv = bias1[d]; act = 1; }   // h: relu
            } else if (AMODE == 4) {
                int cc = (col < N1) ? col : (N1 - 1);
                bv = (half ? bias2 : bias1)[cc]; act = act1;
            } else {
                int cc = (col < Ntot) ? col : (Ntot - 1);
                if (cc < N1) { bv = bias1[cc]; act = act1; }
                else { bv = bias2[cc - N1]; act = act2; }
            }
#pragma unroll
            for (int r = 0; r < 4; ++r) {
                float v = acc[mt][nt][r] + bv;
                if (act == 1) v = fmaxf(v, 0.f);
                else if (act == 2) v = 1.f / (1.f + expf(-v));
                Cs[wr + mt * 16 + quad * 4 + r][cl] = f2s(v);
            }
        }
    }
    __syncthreads();
    if (EPI == 0) {
#pragma unroll
        for (int it = 0; it < 2; ++it) {
            int chunk = tid + it * 256;
            int rl = chunk >> 3;
            int c8 = (chunk & 7) * 8;
            short* dst = (short*)Cl + (size_t)(bm + rl) * ldc + bn + c8;
            *(short4*)dst = *(short4*)&Cs[rl][c8];
            *(short4*)(dst + 4) = *(short4*)&Cs[rl][c8 + 4];
        }
    } else {
        int d0 = bn >> 1;
#pragma unroll
        for (int it = 0; it < 2; ++it) {
            int chunk = tid + it * 256;
            int rl = chunk >> 3;
            int c4 = (chunk & 7) * 4;
            int row = bm + rl;
            const short* xs = (const short*)xbuf + (size_t)row * ldxb + d0 + c4;
            short o[4];
#pragma unroll
            for (int i = 0; i < 4; ++i) {
                float h = s2f(Cs[rl][2 * (c4 + i)]);
                float t = s2f(Cs[rl][2 * (c4 + i) + 1]);
                o[i] = f2s(t * h + (1.f - t) * s2f(xs[i]));
            }
            *(short4*)((short*)Cl + (size_t)row * ldc + d0 + c4) = *(short4*)&o[0];
        }
    }
}

// ---------------------------------------------------------------------------
// Transpose x2-halves of two [NT,*] (stride LDP) matrices into [B,P,S].
// ---------------------------------------------------------------------------
__global__ void k_transpose2(const bf16* __restrict__ srcP, bf16* __restrict__ dstP,
                             const bf16* __restrict__ srcQ, bf16* __restrict__ dstQ) {
    int idx = blockIdx.x * 256 + threadIdx.x;
    if (idx >= B_ * P_ * S_) return;
    const bf16* src = blockIdx.y ? srcQ : srcP;
    bf16* dst = blockIdx.y ? dstQ : dstP;
    int j = idx & (S_ - 1);
    int rest = idx >> 7;
    int p = rest % P_;
    int b = rest / P_;
    dst[idx] = src[((size_t)(b * S_ + j)) * LDP + p];
}

// ---------------------------------------------------------------------------
// sim kernel (validated round 7); inputs stride LDP.
// ---------------------------------------------------------------------------
__global__ __launch_bounds__(256) void k_sim2(const bf16* __restrict__ Pmat,
                                              const bf16* __restrict__ Qmat,
                                              const bf16* __restrict__ PT,
                                              const bf16* __restrict__ QT,
                                              float* __restrict__ SIM) {
    __shared__ float qp[8][P_][2];
    int blk = blockIdx.x;
    int b = blk >> 4;
    int it = blk & 15;
    int tid = threadIdx.x;
    int j = tid & 127, h = tid >> 7;
    int row0 = b * 128 + it * 8;
    for (int x = tid; x < 8 * P_; x += 256) {
        int r = x / P_, c = x - r * P_;
        qp[r][c][0] = b2f(Qmat[(size_t)(row0 + r) * LDP + c]);
        qp[r][c][1] = b2f(Pmat[(size_t)(row0 + r) * LDP + c]);
    }
    __syncthreads();
    const bf16* ptb = PT + (size_t)b * P_ * S_;
    const bf16* qtb = QT + (size_t)b * P_ * S_;
    float acc[4] = {0.f, 0.f, 0.f, 0.f};
    for (int p = 0; p < P_; ++p) {
        float v = b2f(ptb[p * S_ + j]);
        float u = b2f(qtb[p * S_ + j]);
#pragma unroll
        for (int r = 0; r < 4; ++r) {
            int i = h * 4 + r;
            float2 w = *(const float2*)&qp[i][p][0];
            float d = w.x - u;
            acc[r] += w.y * v + __builtin_amdgcn_rcpf(1.f + fabsf(d));
        }
    }
#pragma unroll
    for (int r = 0; r < 4; ++r) {
        int i = it * 8 + h * 4 + r;
        SIM[((size_t)(b * 128 + i)) * S_ + j] = acc[r];
    }
}

// ---------------------------------------------------------------------------
// Softmax weights: Wb[row][128] bf16.
// row<4096 (beta, out row=row): w = softmax_j SIM[row][j].
// row>=4096 (alpha, out row=row): w = softmax_i SIM[b][i][r].
// ---------------------------------------------------------------------------
__global__ __launch_bounds__(128) void k_soft(const float* __restrict__ SIM,
                                              bf16* __restrict__ Wb) {
    int blk = blockIdx.x;
    int kind = blk >> 12;
    int blk2 = blk & 4095;
    int b = blk2 >> 7, r = blk2 & 127;
    int t = threadIdx.x;
    __shared__ float red[128];
    float x = (kind == 0) ? SIM[(size_t)blk2 * S_ + t]
                          : SIM[((size_t)(b * S_ + t)) * S_ + r];
    red[t] = x;
    __syncthreads();
    for (int s = 64; s > 0; s >>= 1) {
        if (t < s) red[t] = fmaxf(red[t], red[t + s]);
        __syncthreads();
    }
    float mx = red[0];
    __syncthreads();
    float ex = expf(x - mx);
    red[t] = ex;
    __syncthreads();
    for (int s = 64; s > 0; s >>= 1) {
        if (t < s) red[t] += red[t + s];
        __syncthreads();
    }
    Wb[(size_t)blk * 128 + t] = __float2bfloat16(ex / red[0]);
}

// ---------------------------------------------------------------------------
// Attention MFMA GEMM: ATT[m] = Wb[m] @ E-half; EA[m] = ATT[m] * E[m] fused.
// Grid: x = row-tile (0..127, 64 rows each; tiles >=64 are alpha),
//       y = col stripe (5 x 64 over LDE). K=128, BK=64.
// B-operand staged transposed from E rows of the opposite sentence.
// ---------------------------------------------------------------------------
__global__ __launch_bounds__(256) void k_attg(const bf16* __restrict__ Wb,
                                              const bf16* __restrict__ E,
                                              bf16* __restrict__ ATT,
                                              bf16* __restrict__ EA) {
    __shared__ short As[64][72];
    __shared__ short Bs[64][72];
    int tid = threadIdx.x;
    int w = tid >> 6, lane = tid & 63, quad = lane >> 4, l16 = lane & 15;
    int m0 = blockIdx.x * 64;
    int kind = (m0 >= NT1) ? 1 : 0;
    int local = m0 - kind * NT1;
    int b = local >> 7;
    int ebase = kind ? (b * 128) : (NT1 + b * 128);   // opposite sentence rows
    int bn = blockIdx.y * 64;
    int wr = (w & 1) * 32, wc = (w >> 1) * 32;
    int ar = tid >> 2, ac = (tid & 3) * 16;

    f32x4 acc[2][2];
#pragma unroll
    for (int i = 0; i < 2; ++i)
#pragma unroll
        for (int j = 0; j < 2; ++j)
#pragma unroll
            for (int r = 0; r < 4; ++r) acc[i][j][r] = 0.f;

    for (int k0 = 0; k0 < 128; k0 += 64) {
        // A tile: Wb rows m0..m0+63, k-chunk
        {
            const short* src = (const short*)Wb + (size_t)(m0 + ar) * 128 + k0 + ac;
#pragma unroll
            for (int i = 0; i < 4; ++i) *(short4*)&As[ar][ac + i * 4] = ((const short4*)src)[i];
        }
        // B tile transposed: Bs[n][k] = E[ebase+k0+k][bn+n]
#pragma unroll
        for (int it = 0; it < 2; ++it) {
            int idx = tid + it * 256;
            int r = idx >> 3;
            int c8 = (idx & 7) * 8;
            const short* src = (const short*)E + (size_t)(ebase + k0 + r) * LDE + bn + c8;
            short4 v0 = ((const short4*)src)[0];
            short4 v1 = ((const short4*)src)[1];
            const short* vp = (const short*)&v0;
#pragma unroll
            for (int i = 0; i < 4; ++i) Bs[c8 + i][r] = vp[i];
            vp = (const short*)&v1;
#pragma unroll
            for (int i = 0; i < 4; ++i) Bs[c8 + 4 + i][r] = vp[i];
        }
        __syncthreads();
        {
            bf16x8 a[2][2], bb[2][2];
#pragma unroll
            for (int mt = 0; mt < 2; ++mt)
#pragma unroll
                for (int ks = 0; ks < 2; ++ks)
                    a[mt][ks] = *(const bf16x8*)&As[wr + mt * 16 + l16][ks * 32 + quad * 8];
#pragma unroll
            for (int nt = 0; nt < 2; ++nt)
#pragma unroll
                for (int ks = 0; ks < 2; ++ks)
                    bb[nt][ks] = *(const bf16x8*)&Bs[wc + nt * 16 + l16][ks * 32 + quad * 8];
#pragma unroll
            for (int mt = 0; mt < 2; ++mt)
#pragma unroll
                for (int nt = 0; nt < 2; ++nt) {
                    acc[mt][nt] = __builtin_amdgcn_mfma_f32_16x16x32_bf16(a[mt][0], bb[nt][0], acc[mt][nt], 0, 0, 0);
                    acc[mt][nt] = __builtin_amdgcn_mfma_f32_16x16x32_bf16(a[mt][1], bb[nt][1], acc[mt][nt], 0, 0, 0);
                }
        }
        __syncthreads();
    }
    // epilogue: stage C, then store ATT and EA = ATT * E[own row]
    short (*Cs)[72] = As;
#pragma unroll
    for (int mt = 0; mt < 2; ++mt)
#pragma unroll
        for (int nt = 0; nt < 2; ++nt) {
            int cl = wc + nt * 16 + l16;
#pragma unroll
            for (int r = 0; r < 4; ++r)
                Cs[wr + mt * 16 + quad * 4 + r][cl] = f2s(acc[mt][nt][r]);
        }
    __syncthreads();
#pragma unroll
    for (int it = 0; it < 2; ++it) {
        int chunk = tid + it * 256;
        int rl = chunk >> 3;
        int c8 = (chunk & 7) * 8;
        int row = m0 + rl;
        short a8[8];
        *(short4*)&a8[0] = *(short4*)&Cs[rl][c8];
        *(short4*)&a8[4] = *(short4*)&Cs[rl][c8 + 4];
        short* adst = (short*)ATT + (size_t)row * LDE + bn + c8;
        *(short4*)adst = *(short4*)&a8[0];
        *(short4*)(adst + 4) = *(short4*)&a8[4];
        const short* es = (const short*)E + (size_t)row * LDE + bn + c8;
        short e8[8];
        *(short4*)&e8[0] = ((const short4*)es)[0];
        *(short4*)&e8[4] = ((const short4*)es)[1];
        short o8[8];
#pragma unroll
        for (int i = 0; i < 8; ++i) o8[i] = f2s(s2f(a8[i]) * s2f(e8[i]));
        short* edst = (short*)EA + (size_t)row * LDE + bn + c8;
        *(short4*)edst = *(short4*)&o8[0];
        *(short4*)(edst + 4) = *(short4*)&o8[4];
    }
}

// ---------------------------------------------------------------------------
// Pool: V [NT, LDP]
// ---------------------------------------------------------------------------
__global__ __launch_bounds__(256) void k_pool(const bf16* __restrict__ V,
                                              float* __restrict__ OUT) {
    int b = blockIdx.x;
    int c = threadIdx.x;
    if (c >= P_) return;
    const bf16* v1 = V + (size_t)(b * S_) * LDP;
    const bf16* v2 = V + (size_t)(NT1 + b * S_) * LDP;
    float mx1 = -INFINITY, mx2 = -INFINITY, s1 = 0.f, s2 = 0.f;
    for (int i = 0; i < S_; ++i) {
        float a = b2f(v1[(size_t)i * LDP + c]);
        mx1 = fmaxf(mx1, a); s1 += a;
        float bb = b2f(v2[(size_t)i * LDP + c]);
        mx2 = fmaxf(mx2, bb); s2 += bb;
    }
    float* o = OUT + (size_t)b * 4 * P_;
    o[c] = mx1; o[P_ + c] = mx2; o[2 * P_ + c] = s1; o[3 * P_ + c] = s2;
}

// Sentinel fill (diagnostic: absmax ~555 => ws_size too small)
__global__ void k_fillf(float* dst, int n, float v) {
    int i = blockIdx.x * 256 + threadIdx.x;
    if (i < n) dst[i] = v;
}

// ---------------------------------------------------------------------------
// Launch
// ---------------------------------------------------------------------------
extern "C" void kernel_launch(void* const* d_in, const int* in_sizes, int n_in,
                              void* d_out, int out_size, void* d_ws, size_t ws_size,
                              hipStream_t stream) {
    const int* x1 = (const int*)d_in[0];
    const int* x2 = (const int*)d_in[1];
    const float* emb = (const float*)d_in[2];
    const float *hw1_Wh = (const float*)d_in[3],  *hw1_bh = (const float*)d_in[4];
    const float *hw1_Wt = (const float*)d_in[5],  *hw1_bt = (const float*)d_in[6];
    const float *hw2_Wh = (const float*)d_in[7],  *hw2_bh = (const float*)d_in[8];
    const float *hw2_Wt = (const float*)d_in[9],  *hw2_bt = (const float*)d_in[10];
    const float *mul_W1 = (const float*)d_in[11], *mul_b1 = (const float*)d_in[12];
    const float *mul_W2 = (const float*)d_in[13], *mul_b2 = (const float*)d_in[14];
    const float *dist_W1 = (const float*)d_in[15], *dist_b1 = (const float*)d_in[16];
    const float *dist_W2 = (const float*)d_in[17], *dist_b2 = (const float*)d_in[18];
    const float *cmp_W1 = (const float*)d_in[19], *cmp_b1 = (const float*)d_in[20];
    const float *cmp_W2 = (const float*)d_in[21], *cmp_b2 = (const float*)d_in[22];
    const float *chw1_Wh = (const float*)d_in[23], *chw1_bh = (const float*)d_in[24];
    const float *chw1_Wt = (const float*)d_in[25], *chw1_bt = (const float*)d_in[26];
    const float *chw2_Wh = (const float*)d_in[27], *chw2_bh = (const float*)d_in[28];
    const float *chw2_Wt = (const float*)d_in[29], *chw2_bt = (const float*)d_in[30];
    const float *agg_W1 = (const float*)d_in[31], *agg_b1 = (const float*)d_in[32];
    const float *agg_W2 = (const float*)d_in[33], *agg_b2 = (const float*)d_in[34];
    const float *out_W = (const float*)d_in[35], *out_b = (const float*)d_in[36];

    // ---- Workspace layout (bf16 elems), all strides 64B-aligned ----
    const size_t nE = (size_t)NT * LDE;        // 2,621,440
    const size_t nP = (size_t)NT * LDP;        // 2,097,152
    const size_t nCht = (size_t)NT * 448;      // 3,670,016
    const size_t nTR = (size_t)B_ * P_ * S_;   //   819,200
    const size_t nWT = 1224704;                // converted bf16 weights
    size_t bf16_elems = 4 * nE + 2 * nP + 2 * nCht + nWT;
    size_t f32_elems = (size_t)B_ * 4 * P_ + 2 * (size_t)B_ * P_ + 200600;
    size_t need = bf16_elems * 2 + f32_elems * 4 + 64;
    if (ws_size < need) {
        k_fillf<<<dim3(1), dim3(256), 0, stream>>>((float*)d_out, B_ * 3, 555.f);
        return;
    }
    bf16* Eb  = (bf16*)d_ws;            // [NT,LDE] embed; later ATT (dead after hw1)
    bf16* X1  = Eb + nE;                // [NT,LDE]
    bf16* X2  = X1 + nE;                // [NT,LDE] final E
    bf16* EA  = X2 + nE;                // [NT,LDE] E*ATT
    bf16* Pb  = EA + nE;                // [NT,LDP]
    bf16* Qb  = Pb + nP;                // [NT,LDP]
    bf16* ChtA = Qb + nP;               // [NT,448]
    bf16* ChtB = ChtA + nCht;           // [NT,448] PT/QT/SIM overlay / V2
    bf16* WTp = ChtB + nCht;
    float* POOL = (float*)(WTp + nWT);
    float* G1 = POOL + (size_t)B_ * 4 * P_;
    float* G2 = G1 + (size_t)B_ * P_;
    float* WT_a1 = G2 + (size_t)B_ * P_;  // [200][800]
    float* WT_a2 = WT_a1 + 160000;        // [200][200]
    float* WT_o  = WT_a2 + 40000;         // [3][200]
    bf16* ATT = Eb;                       // overlay: Eb dead after hw1
    bf16* Wbuf = ChtA;                    // [8192][128] softmax weights overlay
    // overlays inside ChtB:
    bf16* PTb = ChtB;
    bf16* QTb = ChtB + nTR;
    float* SIM = (float*)(ChtB + 2 * nTR);
    bf16* V2 = ChtB;                      // reuse after attention

    // converted-weight sub-buffers, Kpad mult of 64
    bf16* WT_hw1 = WTp + 0;        // 640x320 interleaved h|t
    bf16* WT_hw2 = WTp + 204800;   // 640x320 interleaved
    bf16* WT_md  = WTp + 409600;   // 448x320 (mul_W1 | dist_W1)
    bf16* WT_m2  = WTp + 552960;   // 256x256
    bf16* WT_d2  = WTp + 618496;   // 256x256
    bf16* WT_c2  = WTp + 684032;   // 256x256
    bf16* WT_ch1 = WTp + 749568;   // 448x256 interleaved
    bf16* WT_ch2 = WTp + 864256;   // 448x256 interleaved
    bf16* WT_c1  = WTp + 978944;   // 256x960 (combined cmp_W1)

    dim3 blk256(256);

    // 0. weight conversions
    ConvTable T;
    const float* s1[8] = {hw1_Wh, hw2_Wh, mul_W1, mul_W2, dist_W2, cmp_W2, chw1_Wh, chw2_Wh};
    const float* s2[8] = {hw1_Wt, hw2_Wt, dist_W1, nullptr, nullptr, nullptr, chw1_Wt, chw2_Wt};
    bf16* dsts[8] = {WT_hw1, WT_hw2, WT_md, WT_m2, WT_d2, WT_c2, WT_ch1, WT_ch2};
    int Ks[8]  = {300, 300, 300, 200, 200, 200, 200, 200};
    int N1s[8] = {300, 300, 200, 200, 200, 200, 200, 200};
    int N2s[8] = {300, 300, 200, 0, 0, 0, 200, 200};
    int Kps[8] = {320, 320, 320, 256, 256, 256, 256, 256};
    int Nps[8] = {640, 640, 448, 256, 256, 256, 448, 448};
    int ILs[8] = {1, 1, 0, 0, 0, 0, 1, 1};
    unsigned long long base = 0;
    for (int i = 0; i < 8; ++i) {
        T.W1[i] = s1[i]; T.W2[i] = s2[i]; T.dst[i] = dsts[i];
        T.K[i] = Ks[i]; T.N1[i] = N1s[i]; T.N2[i] = N2s[i]; T.Kpad[i] = Kps[i];
        T.IL[i] = ILs[i];
        T.base[i] = base;
        base += (unsigned long long)Kps[i] * Nps[i];
    }
    T.total = base;   // 978,944
    k_convw<<<dim3((unsigned)((base + 255) / 256)), blk256, 0, stream>>>(T);
    k_convmisc<<<dim3((245760 + 200600 + 255) / 256), blk256, 0, stream>>>(
        cmp_W1, WT_c1, agg_W1, agg_W2, out_W, WT_a1, WT_a2, WT_o);

    // 1. embed gather -> Eb
    k_embed<<<dim3((NT * (LDE / 4) + 255) / 256), blk256, 0, stream>>>(x1, x2, emb, Eb);

    // 2. hw1: A=Eb, interleaved h|t, fused highway (x=Eb) -> X1
    k_gemm<0, 1><<<dim3(128, 10), blk256, 0, stream>>>(
        Eb, nullptr, nullptr, LDE,
        WT_hw1, nullptr, 320, 300, X1, nullptr, LDE, 600, 300,
        hw1_bh, hw1_bt, 1, 2, Eb, LDE);

    // 3. hw2: A=X1, fused highway (x=X1) -> X2
    k_gemm<0, 1><<<dim3(128, 10), blk256, 0, stream>>>(
        X1, nullptr, nullptr, LDE,
        WT_hw2, nullptr, 320, 300, X2, nullptr, LDE, 600, 300,
        hw2_bh, hw2_bt, 1, 2, X1, LDE);

    // 4. md: A=X2 -> ChtA [NT,448] (mul hidden | dist hidden)
    k_gemm<0, 0><<<dim3(128, 7), blk256, 0, stream>>>(
        X2, nullptr, nullptr, LDE,
        WT_md, nullptr, 320, 300, ChtA, nullptr, 448, 400, 200,
        mul_b1, dist_b1, 1, 1, nullptr, 0);

    // 5. m2 + d2 dual: ChtA halves -> Pb, Qb
    k_gemm<4, 0><<<dim3(128, 8), blk256, 0, stream>>>(
        ChtA, nullptr, nullptr, 448,
        WT_m2, WT_d2, 256, 200, Pb, Qb, LDP, 256, 200,
        mul_b2, dist_b2, 1, 1, nullptr, 0);

    // 6. transpose x2-halves into ChtB overlay
    int nTRb = (int)((nTR + 255) / 256);
    k_transpose2<<<dim3(nTRb, 2), blk256, 0, stream>>>(
        Pb + (size_t)NT1 * LDP, PTb, Qb + (size_t)NT1 * LDP, QTb);

    // 7. sim
    k_sim2<<<dim3(B_ * 16), blk256, 0, stream>>>(Pb, Qb, PTb, QTb, SIM);

    // 8. softmax weights (bf16) -> Wbuf (ChtA overlay; md output is consumed)
    k_soft<<<dim3(2 * NT1), dim3(128), 0, stream>>>(SIM, Wbuf);

    // 9. attention MFMA: ATT = Wbuf @ E-half, EA = ATT*E fused; E = X2
    k_attg<<<dim3(128, 5), blk256, 0, stream>>>(Wbuf, X2, ATT, EA);

    // 10. cmp1: virtual K-concat {X2, ATT, EA} -> ChtA hidden [NT,LDP]
    k_gemm<3, 0><<<dim3(128, 4), blk256, 0, stream>>>(
        X2, ATT, EA, LDE,
        WT_c1, nullptr, 960, 300, ChtA, nullptr, LDP, 200, 200,
        cmp_b1, cmp_b1, 1, 1, nullptr, 0);

    // 11. cmp2: ChtA -> Pb (Vv0)
    k_gemm<0, 0><<<dim3(128, 4), blk256, 0, stream>>>(
        ChtA, nullptr, nullptr, LDP,
        WT_c2, nullptr, 256, 200, Pb, nullptr, LDP, 200, 200,
        cmp_b2, cmp_b2, 1, 1, nullptr, 0);

    // 12. ch1: A=Pb, interleaved h|t, fused highway (x=Pb) -> Qb (V1)
    k_gemm<0, 1><<<dim3(128, 7), blk256, 0, stream>>>(
        Pb, nullptr, nullptr, LDP,
        WT_ch1, nullptr, 256, 200, Qb, nullptr, LDP, 400, 200,
        chw1_bh, chw1_bt, 1, 2, Pb, LDP);

    // 13. ch2: A=Qb, fused highway (x=Qb) -> V2 (ChtB reuse)
    k_gemm<0, 1><<<dim3(128, 7), blk256, 0, stream>>>(
        Qb, nullptr, nullptr, LDP,
        WT_ch2, nullptr, 256, 200, V2, nullptr, LDP, 400, 200,
        chw2_bh, chw2_bt, 1, 2, Qb, LDP);

    // 14. pool
    k_pool<<<dim3(B_), blk256, 0, stream>>>(V2, POOL);

    // 15-17. aggregate ff + final linear: wave-per-output skinny GEMMs
    k_skinny<<<dim3(1600), blk256, 0, stream>>>(POOL, WT_a1, agg_b1, G1, B_, P_, 800, 1);
    k_skinny<<<dim3(1600), blk256, 0, stream>>>(G1, WT_a2, agg_b2, G2, B_, P_, 200, 1);
    k_skinny<<<dim3(24), blk256, 0, stream>>>(G2, WT_o, out_b, (float*)d_out, B_, 3, 200, 0);
}